// Round 6
// baseline (1448.550 us; speedup 1.0000x reference)
//
#include <hip/hip_runtime.h>
#include <stdint.h>

// GlobalAttention fused pipeline, MI355X gfx950.
// Round 10: k_conv2m occupancy fix -- LDS cell pad 20->18 u16 (conflict-free,
// tile 44.1 KB) => 3 blocks/CU; launch_bounds(256,3); revert r9's prefetch
// (compiler sank it -- VGPR stayed 128, null result). Inter-block overlap
// hides the per-chunk stage wait.
//   K0: wx,wy -> WT bf16; wqkv -> w8 bf16 [768][256]; rel -> biasT[16][64][64] f32
//   K1: x -> xb LDS once; MFMA qkv GEMM (head-remapped); per-wave attention
//   K2: o,WT -> out1 NCHW bf16 [MFMA, 2 rows/block, 3 blocks/CU]
//   K3: out1 -> bn NCHW bf16 @ d_ws
//   K4: bn -> d_out f32 final [MFMA]

#define B_ 2
#define C_ 256
#define H_ 256
#define W_ 256
#define HW_ 65536

typedef unsigned short u16;
typedef unsigned int u32;
typedef short bf16x8 __attribute__((ext_vector_type(8)));
typedef float f32x4 __attribute__((ext_vector_type(4)));
typedef float f32x16 __attribute__((ext_vector_type(16)));

__device__ __forceinline__ float b2f(u16 h) {
  union { u32 u; float f; } x; x.u = ((u32)h) << 16; return x.f;
}
__device__ __forceinline__ float b2f_lo(u32 u) {
  union { u32 v; float f; } x; x.v = u << 16; return x.f;
}
__device__ __forceinline__ float b2f_hi(u32 u) {
  union { u32 v; float f; } x; x.v = u & 0xffff0000u; return x.f;
}
__device__ __forceinline__ u16 f2b(float f) {  // RNE
  union { float f; u32 u; } x; x.f = f;
  return (u16)((x.u + 0x7fffu + ((x.u >> 16) & 1u)) >> 16);
}
__device__ __forceinline__ u32 pack2(float a, float b) {
  return (u32)f2b(a) | ((u32)f2b(b) << 16);
}
// fast round-half-up bf16 pack: 3 ops via v_perm
__device__ __forceinline__ u32 pack2rn(float a, float b) {
  u32 ua = __float_as_uint(a) + 0x8000u;
  u32 ub = __float_as_uint(b) + 0x8000u;
  return __builtin_amdgcn_perm(ub, ua, 0x07060302u);
}
__device__ __forceinline__ u16 f2brn(float f) {
  return (u16)((__float_as_uint(f) + 0x8000u) >> 16);
}

// ---------------------------------------------------------------------------
// K0: WT bf16 [conv][t][o][c]; wqkv -> w8 bf16 [768][256];
//     rel -> biasT[head][j][i] f32 (16*64*64)
// ---------------------------------------------------------------------------
__global__ __launch_bounds__(256) void k_wt(
    const float* __restrict__ wx, const float* __restrict__ wy,
    const float* __restrict__ wqkv, const float* __restrict__ rel,
    u16* __restrict__ wt, float* __restrict__ biasT)
{
  const int o = blockIdx.x, c = threadIdx.x;
  const float* px = wx + ((size_t)o * 256 + c) * 8;
  const float* py = wy + ((size_t)o * 256 + c) * 8;
#pragma unroll
  for (int t = 0; t < 8; ++t) {
    wt[(size_t)t * 65536 + o * 256 + c]          = f2b(px[t]);
    wt[524288 + (size_t)t * 65536 + o * 256 + c] = f2b(py[t]);
  }
  u16* w8 = wt + 1048576;
#pragma unroll
  for (int t = 0; t < 3; ++t) {
    const int row = o + t * 256;
    w8[(size_t)row * 256 + c] = f2b(wqkv[(size_t)row * 256 + c]);
  }
  // biasT[h][j][i] = rel[ridx(i,j)*16+h]
  const int flat = o * 256 + c;
  const int h = flat >> 12, j = (flat >> 6) & 63, i = flat & 63;
  const int iy = i >> 3, ix = i & 7, jy = j >> 3, jx = j & 7;
  const int ridx = (iy - jy + 7) * 15 + (ix - jx + 7);
  biasT[flat] = rel[ridx * 16 + h];
}

// ---------------------------------------------------------------------------
// K1: qkv (MFMA) + windowed attention (per-wave, barrier-free phase 3).
// Wave w owns heads 4w..4w+3 (q/k/v channels 64w..64w+63).
// ---------------------------------------------------------------------------
__global__ __launch_bounds__(256) void k_attn(
    const float* __restrict__ x, const u16* __restrict__ w8,
    const float* __restrict__ biasT, u16* __restrict__ o_img)
{
  __shared__ __align__(16) union {
    u16 xb[64][264];   // phase 1-2: x window [px][c] bf16
    u16 P[4][4096];    // phase 3: per-wave P tile [i][j], XOR-swizzled
  } U;
  __shared__ __align__(16) u16 q_s[64][264];   // [px][ch], q pre-scaled 0.25
  __shared__ __align__(16) u16 k_s[64][264];   // [px][ch]
  __shared__ __align__(16) u16 v_sT[256][72];  // [ch][px]

  const int tid = threadIdx.x;
  const int nb  = blockIdx.x;
  const int b   = nb >> 10;
  const int hh  = (nb >> 5) & 31;
  const int ww  = nb & 31;
  const int h0  = hh << 3, w0 = ww << 3;

  // ---- phase 1: stage x window -> xb [px][c] bf16 ----
  {
    const int c2 = tid & 127;
    const int half = tid >> 7;
    const float* p0 = x + (((size_t)(b * C_ + 2 * c2)) * H_ + (h0 + half * 4)) * W_ + w0;
    const float* p1 = p0 + (size_t)H_ * W_;
#pragma unroll
    for (int r = 0; r < 4; ++r) {
      const float4 a0 = *(const float4*)(p0 + r * W_);
      const float4 a1 = *(const float4*)(p0 + r * W_ + 4);
      const float4 b0 = *(const float4*)(p1 + r * W_);
      const float4 b1 = *(const float4*)(p1 + r * W_ + 4);
      const float fa[8] = {a0.x, a0.y, a0.z, a0.w, a1.x, a1.y, a1.z, a1.w};
      const float fb[8] = {b0.x, b0.y, b0.z, b0.w, b1.x, b1.y, b1.z, b1.w};
      const int px0 = (half * 4 + r) * 8;
#pragma unroll
      for (int cc = 0; cc < 8; ++cc)
        *(u32*)&U.xb[px0 + cc][2 * c2] = pack2rn(fa[cc], fb[cc]);
    }
  }
  __syncthreads();

  // ---- phase 2: MFMA GEMM, wave w computes rows for its own heads ----
  const int lane = tid & 63, wid = tid >> 6;
  const int n = lane & 31, h5 = lane >> 5;

  f32x16 acc[6][2];
#pragma unroll
  for (int mt = 0; mt < 6; ++mt)
#pragma unroll
    for (int nt = 0; nt < 2; ++nt)
#pragma unroll
      for (int i = 0; i < 16; ++i) acc[mt][nt][i] = 0.f;

#pragma unroll 2
  for (int kb = 0; kb < 16; ++kb) {
    const int k0 = kb * 16;
    bf16x8 bfr[2];
#pragma unroll
    for (int nt = 0; nt < 2; ++nt) {
      union { uint4 u; bf16x8 v; } T;
      T.u = *(const uint4*)&U.xb[nt * 32 + n][k0 + h5 * 8];
      bfr[nt] = T.v;
    }
#pragma unroll
    for (int mt = 0; mt < 6; ++mt) {
      // q rows: wid*64.., k rows: 256+wid*64.., v rows: 512+wid*64..
      const int row = (mt >> 1) * 256 + wid * 64 + (mt & 1) * 32 + n;
      union { uint4 u; bf16x8 v; } A;
      A.u = *(const uint4*)(w8 + (size_t)row * 256 + k0 + h5 * 8);
      acc[mt][0] = __builtin_amdgcn_mfma_f32_32x32x16_bf16(A.v, bfr[0], acc[mt][0], 0, 0, 0);
      acc[mt][1] = __builtin_amdgcn_mfma_f32_32x32x16_bf16(A.v, bfr[1], acc[mt][1], 0, 0, 0);
    }
  }

  // ---- phase 2.5: scatter q,k -> [px][ch] (u32 pairs); v -> [ch][px] ----
  const int chb0 = wid * 64 + 4 * h5;
#pragma unroll
  for (int mt = 0; mt < 4; ++mt) {
    u16 (*dst)[264] = (mt < 2) ? q_s : k_s;
    const float qs = (mt < 2) ? 0.25f : 1.0f;
    const int chb = chb0 + (mt & 1) * 32;
#pragma unroll
    for (int nt = 0; nt < 2; ++nt) {
      const int px = nt * 32 + n;
#pragma unroll
      for (int m = 0; m < 8; ++m) {
        const int ch = chb + ((2 * m) & 3) + 8 * (m >> 1);
        *(u32*)&dst[px][ch] =
            pack2rn(acc[mt][nt][2 * m] * qs, acc[mt][nt][2 * m + 1] * qs);
      }
    }
  }
#pragma unroll
  for (int mt = 4; mt < 6; ++mt) {
    const int chb = chb0 + (mt & 1) * 32;
#pragma unroll
    for (int nt = 0; nt < 2; ++nt) {
      const int px = nt * 32 + n;
#pragma unroll
      for (int r = 0; r < 16; ++r) {
        const int ch = chb + (r & 3) + 8 * (r >> 2);
        v_sT[ch][px] = f2brn(acc[mt][nt][r]);
      }
    }
  }
  __syncthreads();  // protect xb->P union across all waves

  // ---- phase 3: per-wave attention, 4 heads, no barriers ----
  u16* Pw = U.P[wid];
  const int il = lane & 15, jg = lane >> 4;

  for (int hl = 0; hl < 4; ++hl) {
    const int head = wid * 4 + hl;
    const int hb = head * 16;

    // QK^T swapped: S^T[j][i] = K[j][d] . Q^T[d][i]   (scale folded into q)
    bf16x8 ak[2], bq[2];
#pragma unroll
    for (int jt = 0; jt < 2; ++jt) {
      union { uint4 u; bf16x8 v; } T;
      T.u = *(const uint4*)&k_s[jt * 32 + n][hb + h5 * 8];
      ak[jt] = T.v;
    }
#pragma unroll
    for (int it = 0; it < 2; ++it) {
      union { uint4 u; bf16x8 v; } T;
      T.u = *(const uint4*)&q_s[it * 32 + n][hb + h5 * 8];
      bq[it] = T.v;
    }
    f32x16 zro;
#pragma unroll
    for (int e = 0; e < 16; ++e) zro[e] = 0.f;
    f32x16 s[2][2];
#pragma unroll
    for (int jt = 0; jt < 2; ++jt)
#pragma unroll
      for (int it = 0; it < 2; ++it)
        s[jt][it] = __builtin_amdgcn_mfma_f32_32x32x16_bf16(ak[jt], bq[it], zro, 0, 0, 0);

    // + bias (biasT[head][j][i], coalesced over i = lanes)
    const float* bT = biasT + head * 4096;
#pragma unroll
    for (int jt = 0; jt < 2; ++jt)
#pragma unroll
      for (int it = 0; it < 2; ++it)
#pragma unroll
        for (int r = 0; r < 16; ++r) {
          const int j = jt * 32 + (r & 3) + 8 * (r >> 2) + 4 * h5;
          s[jt][it][r] += bT[j * 64 + it * 32 + n];
        }

    // in-lane softmax per i-row (lane pair n, n+32 holds the two j-halves)
#pragma unroll
    for (int it = 0; it < 2; ++it) {
      const int i = it * 32 + n;
      float mx = s[0][it][0];
#pragma unroll
      for (int jt = 0; jt < 2; ++jt)
#pragma unroll
        for (int r = 0; r < 16; ++r) mx = fmaxf(mx, s[jt][it][r]);
      mx = fmaxf(mx, __shfl_xor(mx, 32));
      float sum = 0.f;
#pragma unroll
      for (int jt = 0; jt < 2; ++jt)
#pragma unroll
        for (int r = 0; r < 16; ++r) {
          const float p = __expf(s[jt][it][r] - mx);
          s[jt][it][r] = p;
          sum += p;
        }
      sum += __shfl_xor(sum, 32);
      const float rs = 1.0f / sum;
      const u32 rowoff = (u32)(i * 128);
      const u32 swz = (u32)((i & 7) << 4);
#pragma unroll
      for (int jt = 0; jt < 2; ++jt)
#pragma unroll
        for (int m = 0; m < 8; ++m) {
          const int j = jt * 32 + ((2 * m) & 3) + 8 * (m >> 1) + 4 * h5;
          const u32 off = (rowoff + (u32)(j * 2)) ^ swz;
          *(u32*)((char*)Pw + off) =
              pack2rn(s[jt][it][2 * m] * rs, s[jt][it][2 * m + 1] * rs);
        }
    }

    // PV: O[64i][16d] = P[64x64] . V[64x16]  (16x16x32, N = d = 16 exactly)
    bf16x8 bv[2];
#pragma unroll
    for (int ks = 0; ks < 2; ++ks) {
      union { uint4 u; bf16x8 v; } T;
      T.u = *(const uint4*)&v_sT[hb + il][ks * 32 + jg * 8];
      bv[ks] = T.v;
    }
#pragma unroll
    for (int it2 = 0; it2 < 4; ++it2) {
      f32x4 pv = {0.f, 0.f, 0.f, 0.f};
#pragma unroll
      for (int ks = 0; ks < 2; ++ks) {
        const int i = it2 * 16 + il;
        const u32 off =
            ((u32)(i * 128 + ks * 64 + jg * 16)) ^ ((u32)((i & 7) << 4));
        union { uint4 u; bf16x8 v; } A;
        A.u = *(const uint4*)((const char*)Pw + off);
        pv = __builtin_amdgcn_mfma_f32_16x16x32_bf16(A.v, bv[ks], pv, 0, 0, 0);
      }
#pragma unroll
      for (int rr = 0; rr < 4; ++rr) {
        const int i = it2 * 16 + jg * 4 + rr;
        const int iy = i >> 3, ix = i & 7;
        o_img[(((size_t)(b * H_ + h0 + iy)) * W_ + (w0 + ix)) * C_ + hb + il] =
            f2brn(pv[rr]);
      }
    }
  }
}

// ---------------------------------------------------------------------------
// K2 (MFMA): out1 = ox + oy + bx + by.
// Round 10: cell pad 18 u16 (36 B, gcd(9,32)=1 -> conflict-free), tile 44.1 KB
// -> 3 blocks/CU; launch_bounds(256,3); direct 2-barrier staging (r8 style)
// with precomputed per-thread geometry; XCD swizzle kept.
// ---------------------------------------------------------------------------
__global__ __launch_bounds__(256, 3) void k_conv2m(
    const u16* __restrict__ o_nhwc, const u16* __restrict__ wt,
    const float* __restrict__ bxg, const float* __restrict__ byg,
    u16* __restrict__ out1)
{
  __shared__ u16 tile[9 * 136 * 18];   // 44.1 KB
  __shared__ float bias_l[128];

  const int tid = threadIdx.x;
  // XCD swizzle: 1024 blocks = 8 XCDs x 128 contiguous ids (bijective)
  const int nb = (blockIdx.x & 7) * 128 + (blockIdx.x >> 3);
  const int wh = nb & 1, oh = (nb >> 1) & 1, hg = (nb >> 2) & 127, b = nb >> 9;
  const int h0 = hg << 1;             // 2 output rows h0, h0+1
  const int ob = oh * 128, wb0 = wh * 128;
  const int lane = tid & 63, wid = tid >> 6;
  const int o64 = (wid & 1) * 64;         // wave M-tile
  const int w64 = ((wid >> 1) & 1) * 64;  // wave N (w) tile
  const int n = lane & 31, h5 = lane >> 5;

  if (tid < 128) bias_l[tid] = bxg[ob + tid] + byg[ob + tid];

  // ---- staging geometry: 1224 cells, 5 per thread (last round partial) ----
  const u16* srcp[5];
  u32 dstoff[5];
#pragma unroll
  for (int k = 0; k < 5; ++k) {
    const int e = tid + (k << 8);
    srcp[k] = nullptr;
    dstoff[k] = 0;
    if (e < 1224) {
      const int r = e / 136, wi = e - r * 136;
      const int hp = h0 - 3 + r;
      const int wp = wb0 + wi - 4;
      dstoff[k] = (u32)((r * 136 + wi) * 18);
      if (hp >= 0 && hp <= 256 && wp >= 0 && wp <= 256) {
        const int hr = (hp == 256) ? 254 : hp;
        const int wr = (wp == 256) ? 254 : wp;
        srcp[k] = o_nhwc + (((size_t)(b * H_ + hr)) * W_ + wr) * C_;
      }
    }
  }

  f32x16 acc[2][2][2];   // [row][mt][nt]
#pragma unroll
  for (int r2 = 0; r2 < 2; ++r2)
#pragma unroll
    for (int mt = 0; mt < 2; ++mt)
#pragma unroll
      for (int nt = 0; nt < 2; ++nt)
#pragma unroll
        for (int i = 0; i < 16; ++i) acc[r2][mt][nt][i] = 0.f;

  for (int cb = 0; cb < 16; ++cb) {
    const int c0 = cb * 16;
    __syncthreads();
    // ---- stage 9 rows x 136 w x 16 c (NHWC source: 32B contiguous) ----
#pragma unroll
    for (int k = 0; k < 5; ++k) {
      if (tid + (k << 8) < 1224) {
        uint4 A = make_uint4(0, 0, 0, 0), Bv = A;
        if (srcp[k]) {
          A  = *(const uint4*)(srcp[k] + c0);
          Bv = *(const uint4*)(srcp[k] + c0 + 8);
        }
        u16* d = &tile[dstoff[k]];
        *(uint2*)(d)      = make_uint2(A.x, A.y);
        *(uint2*)(d + 4)  = make_uint2(A.z, A.w);
        *(uint2*)(d + 8)  = make_uint2(Bv.x, Bv.y);
        *(uint2*)(d + 12) = make_uint2(Bv.z, Bv.w);
      }
    }
    __syncthreads();
    // ---- compute: 2 convs x 8 taps, K=16 channels, BOTH rows per wave ----
#pragma unroll
    for (int cv = 0; cv < 2; ++cv) {
      const u16* wbase = wt + (size_t)cv * 524288;
#pragma unroll
      for (int t = 0; t < 8; ++t) {
        bf16x8 a[2];
#pragma unroll
        for (int mt = 0; mt < 2; ++mt) {
          const int o = ob + o64 + mt * 32 + n;
          union { uint4 u; bf16x8 v; } Uu;
          Uu.u = *(const uint4*)(wbase + ((size_t)(t * 256 + o)) * 256 + c0 + h5 * 8);
          a[mt] = Uu.v;
        }
        bf16x8 bb[2][2];   // [row][nt]
#pragma unroll
        for (int r2 = 0; r2 < 2; ++r2)
#pragma unroll
          for (int nt = 0; nt < 2; ++nt) {
            const int rr = cv ? (r2 + 3) : (r2 + t);
            const int wi = w64 + nt * 32 + n + (cv ? (t + 1) : 4);
            const u16* p = &tile[(rr * 136 + wi) * 18 + h5 * 8];
            union { uint2 u[2]; bf16x8 v; } Uu;
            Uu.u[0] = *(const uint2*)p;
            Uu.u[1] = *(const uint2*)(p + 4);
            bb[r2][nt] = Uu.v;
          }
#pragma unroll
        for (int r2 = 0; r2 < 2; ++r2) {
          acc[r2][0][0] = __builtin_amdgcn_mfma_f32_32x32x16_bf16(a[0], bb[r2][0], acc[r2][0][0], 0, 0, 0);
          acc[r2][0][1] = __builtin_amdgcn_mfma_f32_32x32x16_bf16(a[0], bb[r2][1], acc[r2][0][1], 0, 0, 0);
          acc[r2][1][0] = __builtin_amdgcn_mfma_f32_32x32x16_bf16(a[1], bb[r2][0], acc[r2][1][0], 0, 0, 0);
          acc[r2][1][1] = __builtin_amdgcn_mfma_f32_32x32x16_bf16(a[1], bb[r2][1], acc[r2][1][1], 0, 0, 0);
        }
      }
    }
  }
  // ---- epilogue: +bias, bf16, NCHW, both rows ----
#pragma unroll
  for (int r2 = 0; r2 < 2; ++r2)
#pragma unroll
    for (int mt = 0; mt < 2; ++mt)
#pragma unroll
      for (int nt = 0; nt < 2; ++nt)
#pragma unroll
        for (int r = 0; r < 16; ++r) {
          const int om = o64 + mt * 32 + (r & 3) + 8 * (r >> 2) + 4 * h5;
          const int o = ob + om;
          const int wg = wb0 + w64 + nt * 32 + n;
          const float v = acc[r2][mt][nt][r] + bias_l[om];
          out1[(((size_t)(b * C_ + o)) * H_ + (h0 + r2)) * W_ + wg] = f2b(v);
        }
}

// ---------------------------------------------------------------------------
// K3: depthwise 8x8 conv + BN (unchanged).
// ---------------------------------------------------------------------------
__global__ __launch_bounds__(256) void k_dwbn(
    const u16* __restrict__ out1, const float* __restrict__ wdw,
    const float* __restrict__ gam, const float* __restrict__ bet,
    const float* __restrict__ mea, const float* __restrict__ var,
    u16* __restrict__ bno)
{
  __shared__ u16 tile[23][264];
  const int tid = threadIdx.x, nb = blockIdx.x;
  const int c = nb & 255, ht = (nb >> 8) & 15, b = nb >> 12;
  const int h0 = ht * 16;

  for (int e = tid; e < 23 * 264; e += 256) {
    const int tr = e / 264, tc = e % 264;
    const int r = h0 - 3 + tr;
    const int cg = tc - 3;
    u16 v = 0;
    if (r >= 0 && r <= 256 && cg >= 0 && cg <= 256) {
      const int rr = (r == 256) ? 254 : r;
      const int cgm = (cg == 256) ? 254 : cg;
      v = out1[(((size_t)(b * C_ + c)) * H_ + rr) * W_ + cgm];
    }
    tile[tr][tc] = v;
  }
  float wk[64];
#pragma unroll
  for (int k2 = 0; k2 < 64; ++k2) wk[k2] = wdw[c * 64 + k2];
  const float scl = gam[c] / sqrtf(var[c] + 1e-5f);
  const float shf = bet[c] - mea[c] * scl;
  __syncthreads();

  const int wg = tid & 31, hg = tid >> 5;
  const int w0 = wg * 8;
#pragma unroll
  for (int k = 0; k < 2; ++k) {
    const int hl = hg * 2 + k;
    float a[8];
#pragma unroll
    for (int s = 0; s < 8; ++s) a[s] = 0.f;
#pragma unroll
    for (int i = 0; i < 8; ++i) {
      const uint4 va = *(const uint4*)&tile[hl + i][w0];
      const uint4 vb = *(const uint4*)&tile[hl + i][w0 + 8];
      float f[16];
      f[0] = b2f_lo(va.x);  f[1] = b2f_hi(va.x);  f[2] = b2f_lo(va.y);  f[3] = b2f_hi(va.y);
      f[4] = b2f_lo(va.z);  f[5] = b2f_hi(va.z);  f[6] = b2f_lo(va.w);  f[7] = b2f_hi(va.w);
      f[8] = b2f_lo(vb.x);  f[9] = b2f_hi(vb.x);  f[10] = b2f_lo(vb.y); f[11] = b2f_hi(vb.y);
      f[12] = b2f_lo(vb.z); f[13] = b2f_hi(vb.z); f[14] = b2f_lo(vb.w); f[15] = b2f_hi(vb.w);
#pragma unroll
      for (int j = 0; j < 8; ++j) {
        const float wv = wk[i * 8 + j];
#pragma unroll
        for (int s = 0; s < 8; ++s) a[s] += f[s + j] * wv;
      }
    }
    uint4 uv;
    uv.x = pack2(a[0] * scl + shf, a[1] * scl + shf);
    uv.y = pack2(a[2] * scl + shf, a[3] * scl + shf);
    uv.z = pack2(a[4] * scl + shf, a[5] * scl + shf);
    uv.w = pack2(a[6] * scl + shf, a[7] * scl + shf);
    *(uint4*)&bno[(((size_t)(b * C_ + c)) * H_ + h0 + hl) * W_ + w0] = uv;
  }
}

// ---------------------------------------------------------------------------
// K4 (MFMA): 1x1 projection (unchanged). Output f32.
// ---------------------------------------------------------------------------
__global__ __launch_bounds__(256) void k_projm(
    const u16* __restrict__ bn, const float* __restrict__ wp, float* __restrict__ out)
{
  const int tid = threadIdx.x, nb = blockIdx.x;
  const int oh = nb & 1;
  const int pb = nb >> 1;            // 0..1023
  const int b  = pb >> 9;
  const int px0 = (pb & 511) << 7;   // 128-px slab (linear in NCHW plane)
  const int lane = tid & 63, wid = tid >> 6;
  const int wo = (wid >> 1) * 64, wpx = (wid & 1) * 64;
  const int n = lane & 31, h5 = lane >> 5;
  const int ob = oh * 128;
  const int pxl = px0 + wpx + n;

  f32x16 acc[2][2];
#pragma unroll
  for (int mt = 0; mt < 2; ++mt)
#pragma unroll
    for (int nt = 0; nt < 2; ++nt)
#pragma unroll
      for (int i = 0; i < 16; ++i) acc[mt][nt][i] = 0.f;

  const u16* bnb = bn + (size_t)b * C_ * HW_;
#pragma unroll 2
  for (int cb = 0; cb < 16; ++cb) {
    const int c0 = cb * 16;
    bf16x8 a[2];
#pragma unroll
    for (int mt = 0; mt < 2; ++mt) {
      const int row = ob + wo + mt * 32 + n;
      const float4 w0v = *(const float4*)&wp[(size_t)row * 256 + c0 + h5 * 8];
      const float4 w1v = *(const float4*)&wp[(size_t)row * 256 + c0 + h5 * 8 + 4];
      union { u32 u[4]; bf16x8 v; } T;
      T.u[0] = pack2rn(w0v.x, w0v.y);
      T.u[1] = pack2rn(w0v.z, w0v.w);
      T.u[2] = pack2rn(w1v.x, w1v.y);
      T.u[3] = pack2rn(w1v.z, w1v.w);
      a[mt] = T.v;
    }
    bf16x8 bb[2];
#pragma unroll
    for (int nt = 0; nt < 2; ++nt) {
      const u16* sp = bnb + (size_t)(c0 + h5 * 8) * HW_ + (pxl + nt * 32);
      const u32 e0 = sp[0 * HW_], e1 = sp[1 * HW_], e2 = sp[2 * HW_], e3 = sp[3 * HW_];
      const u32 e4 = sp[4 * HW_], e5 = sp[5 * HW_], e6 = sp[6 * HW_], e7 = sp[7 * HW_];
      union { u32 u[4]; bf16x8 v; } T;
      T.u[0] = e0 | (e1 << 16);
      T.u[1] = e2 | (e3 << 16);
      T.u[2] = e4 | (e5 << 16);
      T.u[3] = e6 | (e7 << 16);
      bb[nt] = T.v;
    }
    acc[0][0] = __builtin_amdgcn_mfma_f32_32x32x16_bf16(a[0], bb[0], acc[0][0], 0, 0, 0);
    acc[0][1] = __builtin_amdgcn_mfma_f32_32x32x16_bf16(a[0], bb[1], acc[0][1], 0, 0, 0);
    acc[1][0] = __builtin_amdgcn_mfma_f32_32x32x16_bf16(a[1], bb[0], acc[1][0], 0, 0, 0);
    acc[1][1] = __builtin_amdgcn_mfma_f32_32x32x16_bf16(a[1], bb[1], acc[1][1], 0, 0, 0);
  }
#pragma unroll
  for (int mt = 0; mt < 2; ++mt)
#pragma unroll
    for (int nt = 0; nt < 2; ++nt)
#pragma unroll
      for (int r = 0; r < 16; ++r) {
        const int o = ob + wo + mt * 32 + (r & 3) + 8 * (r >> 2) + 4 * h5;
        out[((size_t)(b * C_ + o)) * HW_ + (pxl + nt * 32)] = acc[mt][nt][r];
      }
}

// ---------------------------------------------------------------------------
extern "C" void kernel_launch(void* const* d_in, const int* in_sizes, int n_in,
                              void* d_out, int out_size, void* d_ws, size_t ws_size,
                              hipStream_t stream)
{
  const float* x     = (const float*)d_in[0];
  const float* wqkv  = (const float*)d_in[1];
  const float* rel   = (const float*)d_in[2];
  const float* wax   = (const float*)d_in[3];
  const float* bax   = (const float*)d_in[4];
  const float* way   = (const float*)d_in[5];
  const float* bay   = (const float*)d_in[6];
  const float* wdw   = (const float*)d_in[7];
  const float* gam   = (const float*)d_in[8];
  const float* bet   = (const float*)d_in[9];
  const float* mea   = (const float*)d_in[10];
  const float* var   = (const float*)d_in[11];
  const float* wproj = (const float*)d_in[12];
  float* out = (float*)d_out;

  const size_t N = (size_t)B_ * C_ * H_ * W_;
  u16* oNHWC  = (u16*)d_out;        // bf16 o, NHWC (first half of f32 out)
  u16* out1b  = (u16*)d_out + N;    // bf16 out1, NCHW (second half)
  u16* wtbuf  = (u16*)d_ws;         // WT 2MB + w8 384KB (bf16)
  float* biasT = (float*)((char*)d_ws + 2490368);  // 256KB, after WT+w8
  u16* bnbuf  = (u16*)d_ws;         // bn NCHW bf16 (reuses region after K2)

  hipLaunchKernelGGL(k_wt,     dim3(256),  dim3(256), 0, stream, wax, way, wqkv, rel, wtbuf, biasT);
  hipLaunchKernelGGL(k_attn,   dim3(2048), dim3(256), 0, stream, x, wtbuf + 1048576, biasT, oNHWC);
  hipLaunchKernelGGL(k_conv2m, dim3(1024), dim3(256), 0, stream, oNHWC, wtbuf, bax, bay, out1b);
  hipLaunchKernelGGL(k_dwbn,   dim3(8192), dim3(256), 0, stream, out1b, wdw, gam, bet, mea, var, bnbuf);
  hipLaunchKernelGGL(k_projm,  dim3(2048), dim3(256), 0, stream, bnbuf, wproj, out);
}

// Round 7
// 981.974 us; speedup vs baseline: 1.4751x; 1.4751x over previous
//
#include <hip/hip_runtime.h>
#include <stdint.h>

// GlobalAttention fused pipeline, MI355X gfx950.
// Round 11: k_conv2m = r8 config (pad 20, launch_bounds(256,2), 2 blocks/CU)
// + r9 async-STAGE split FIXED with sched_barrier(0) pin so the compiler
// cannot sink the prefetch loads past the MFMA cluster (r9 failure mode:
// VGPR stayed 128 => loads sunk => null). r10's 3-block attempt spilled
// acc to scratch (VGPR 84, WRITE_SIZE +67%) -- reverted.
//   K0: wx,wy -> WT bf16; wqkv -> w8 bf16 [768][256]; rel -> biasT[16][64][64] f32
//   K1: x -> xb LDS once; MFMA qkv GEMM (head-remapped); per-wave attention
//   K2: o,WT -> out1 NCHW bf16 [MFMA, 2 rows/block, pinned prefetch]
//   K3: out1 -> bn NCHW bf16 @ d_ws
//   K4: bn -> d_out f32 final [MFMA]

#define B_ 2
#define C_ 256
#define H_ 256
#define W_ 256
#define HW_ 65536

typedef unsigned short u16;
typedef unsigned int u32;
typedef short bf16x8 __attribute__((ext_vector_type(8)));
typedef float f32x4 __attribute__((ext_vector_type(4)));
typedef float f32x16 __attribute__((ext_vector_type(16)));

__device__ __forceinline__ float b2f(u16 h) {
  union { u32 u; float f; } x; x.u = ((u32)h) << 16; return x.f;
}
__device__ __forceinline__ float b2f_lo(u32 u) {
  union { u32 v; float f; } x; x.v = u << 16; return x.f;
}
__device__ __forceinline__ float b2f_hi(u32 u) {
  union { u32 v; float f; } x; x.v = u & 0xffff0000u; return x.f;
}
__device__ __forceinline__ u16 f2b(float f) {  // RNE
  union { float f; u32 u; } x; x.f = f;
  return (u16)((x.u + 0x7fffu + ((x.u >> 16) & 1u)) >> 16);
}
__device__ __forceinline__ u32 pack2(float a, float b) {
  return (u32)f2b(a) | ((u32)f2b(b) << 16);
}
// fast round-half-up bf16 pack: 3 ops via v_perm
__device__ __forceinline__ u32 pack2rn(float a, float b) {
  u32 ua = __float_as_uint(a) + 0x8000u;
  u32 ub = __float_as_uint(b) + 0x8000u;
  return __builtin_amdgcn_perm(ub, ua, 0x07060302u);
}
__device__ __forceinline__ u16 f2brn(float f) {
  return (u16)((__float_as_uint(f) + 0x8000u) >> 16);
}

// ---------------------------------------------------------------------------
// K0: WT bf16 [conv][t][o][c]; wqkv -> w8 bf16 [768][256];
//     rel -> biasT[head][j][i] f32 (16*64*64)
// ---------------------------------------------------------------------------
__global__ __launch_bounds__(256) void k_wt(
    const float* __restrict__ wx, const float* __restrict__ wy,
    const float* __restrict__ wqkv, const float* __restrict__ rel,
    u16* __restrict__ wt, float* __restrict__ biasT)
{
  const int o = blockIdx.x, c = threadIdx.x;
  const float* px = wx + ((size_t)o * 256 + c) * 8;
  const float* py = wy + ((size_t)o * 256 + c) * 8;
#pragma unroll
  for (int t = 0; t < 8; ++t) {
    wt[(size_t)t * 65536 + o * 256 + c]          = f2b(px[t]);
    wt[524288 + (size_t)t * 65536 + o * 256 + c] = f2b(py[t]);
  }
  u16* w8 = wt + 1048576;
#pragma unroll
  for (int t = 0; t < 3; ++t) {
    const int row = o + t * 256;
    w8[(size_t)row * 256 + c] = f2b(wqkv[(size_t)row * 256 + c]);
  }
  // biasT[h][j][i] = rel[ridx(i,j)*16+h]
  const int flat = o * 256 + c;
  const int h = flat >> 12, j = (flat >> 6) & 63, i = flat & 63;
  const int iy = i >> 3, ix = i & 7, jy = j >> 3, jx = j & 7;
  const int ridx = (iy - jy + 7) * 15 + (ix - jx + 7);
  biasT[flat] = rel[ridx * 16 + h];
}

// ---------------------------------------------------------------------------
// K1: qkv (MFMA) + windowed attention (per-wave, barrier-free phase 3).
// Wave w owns heads 4w..4w+3 (q/k/v channels 64w..64w+63).
// ---------------------------------------------------------------------------
__global__ __launch_bounds__(256) void k_attn(
    const float* __restrict__ x, const u16* __restrict__ w8,
    const float* __restrict__ biasT, u16* __restrict__ o_img)
{
  __shared__ __align__(16) union {
    u16 xb[64][264];   // phase 1-2: x window [px][c] bf16
    u16 P[4][4096];    // phase 3: per-wave P tile [i][j], XOR-swizzled
  } U;
  __shared__ __align__(16) u16 q_s[64][264];   // [px][ch], q pre-scaled 0.25
  __shared__ __align__(16) u16 k_s[64][264];   // [px][ch]
  __shared__ __align__(16) u16 v_sT[256][72];  // [ch][px]

  const int tid = threadIdx.x;
  const int nb  = blockIdx.x;
  const int b   = nb >> 10;
  const int hh  = (nb >> 5) & 31;
  const int ww  = nb & 31;
  const int h0  = hh << 3, w0 = ww << 3;

  // ---- phase 1: stage x window -> xb [px][c] bf16 ----
  {
    const int c2 = tid & 127;
    const int half = tid >> 7;
    const float* p0 = x + (((size_t)(b * C_ + 2 * c2)) * H_ + (h0 + half * 4)) * W_ + w0;
    const float* p1 = p0 + (size_t)H_ * W_;
#pragma unroll
    for (int r = 0; r < 4; ++r) {
      const float4 a0 = *(const float4*)(p0 + r * W_);
      const float4 a1 = *(const float4*)(p0 + r * W_ + 4);
      const float4 b0 = *(const float4*)(p1 + r * W_);
      const float4 b1 = *(const float4*)(p1 + r * W_ + 4);
      const float fa[8] = {a0.x, a0.y, a0.z, a0.w, a1.x, a1.y, a1.z, a1.w};
      const float fb[8] = {b0.x, b0.y, b0.z, b0.w, b1.x, b1.y, b1.z, b1.w};
      const int px0 = (half * 4 + r) * 8;
#pragma unroll
      for (int cc = 0; cc < 8; ++cc)
        *(u32*)&U.xb[px0 + cc][2 * c2] = pack2rn(fa[cc], fb[cc]);
    }
  }
  __syncthreads();

  // ---- phase 2: MFMA GEMM, wave w computes rows for its own heads ----
  const int lane = tid & 63, wid = tid >> 6;
  const int n = lane & 31, h5 = lane >> 5;

  f32x16 acc[6][2];
#pragma unroll
  for (int mt = 0; mt < 6; ++mt)
#pragma unroll
    for (int nt = 0; nt < 2; ++nt)
#pragma unroll
      for (int i = 0; i < 16; ++i) acc[mt][nt][i] = 0.f;

#pragma unroll 2
  for (int kb = 0; kb < 16; ++kb) {
    const int k0 = kb * 16;
    bf16x8 bfr[2];
#pragma unroll
    for (int nt = 0; nt < 2; ++nt) {
      union { uint4 u; bf16x8 v; } T;
      T.u = *(const uint4*)&U.xb[nt * 32 + n][k0 + h5 * 8];
      bfr[nt] = T.v;
    }
#pragma unroll
    for (int mt = 0; mt < 6; ++mt) {
      // q rows: wid*64.., k rows: 256+wid*64.., v rows: 512+wid*64..
      const int row = (mt >> 1) * 256 + wid * 64 + (mt & 1) * 32 + n;
      union { uint4 u; bf16x8 v; } A;
      A.u = *(const uint4*)(w8 + (size_t)row * 256 + k0 + h5 * 8);
      acc[mt][0] = __builtin_amdgcn_mfma_f32_32x32x16_bf16(A.v, bfr[0], acc[mt][0], 0, 0, 0);
      acc[mt][1] = __builtin_amdgcn_mfma_f32_32x32x16_bf16(A.v, bfr[1], acc[mt][1], 0, 0, 0);
    }
  }

  // ---- phase 2.5: scatter q,k -> [px][ch] (u32 pairs); v -> [ch][px] ----
  const int chb0 = wid * 64 + 4 * h5;
#pragma unroll
  for (int mt = 0; mt < 4; ++mt) {
    u16 (*dst)[264] = (mt < 2) ? q_s : k_s;
    const float qs = (mt < 2) ? 0.25f : 1.0f;
    const int chb = chb0 + (mt & 1) * 32;
#pragma unroll
    for (int nt = 0; nt < 2; ++nt) {
      const int px = nt * 32 + n;
#pragma unroll
      for (int m = 0; m < 8; ++m) {
        const int ch = chb + ((2 * m) & 3) + 8 * (m >> 1);
        *(u32*)&dst[px][ch] =
            pack2rn(acc[mt][nt][2 * m] * qs, acc[mt][nt][2 * m + 1] * qs);
      }
    }
  }
#pragma unroll
  for (int mt = 4; mt < 6; ++mt) {
    const int chb = chb0 + (mt & 1) * 32;
#pragma unroll
    for (int nt = 0; nt < 2; ++nt) {
      const int px = nt * 32 + n;
#pragma unroll
      for (int r = 0; r < 16; ++r) {
        const int ch = chb + (r & 3) + 8 * (r >> 2);
        v_sT[ch][px] = f2brn(acc[mt][nt][r]);
      }
    }
  }
  __syncthreads();  // protect xb->P union across all waves

  // ---- phase 3: per-wave attention, 4 heads, no barriers ----
  u16* Pw = U.P[wid];
  const int il = lane & 15, jg = lane >> 4;

  for (int hl = 0; hl < 4; ++hl) {
    const int head = wid * 4 + hl;
    const int hb = head * 16;

    // QK^T swapped: S^T[j][i] = K[j][d] . Q^T[d][i]   (scale folded into q)
    bf16x8 ak[2], bq[2];
#pragma unroll
    for (int jt = 0; jt < 2; ++jt) {
      union { uint4 u; bf16x8 v; } T;
      T.u = *(const uint4*)&k_s[jt * 32 + n][hb + h5 * 8];
      ak[jt] = T.v;
    }
#pragma unroll
    for (int it = 0; it < 2; ++it) {
      union { uint4 u; bf16x8 v; } T;
      T.u = *(const uint4*)&q_s[it * 32 + n][hb + h5 * 8];
      bq[it] = T.v;
    }
    f32x16 zro;
#pragma unroll
    for (int e = 0; e < 16; ++e) zro[e] = 0.f;
    f32x16 s[2][2];
#pragma unroll
    for (int jt = 0; jt < 2; ++jt)
#pragma unroll
      for (int it = 0; it < 2; ++it)
        s[jt][it] = __builtin_amdgcn_mfma_f32_32x32x16_bf16(ak[jt], bq[it], zro, 0, 0, 0);

    // + bias (biasT[head][j][i], coalesced over i = lanes)
    const float* bT = biasT + head * 4096;
#pragma unroll
    for (int jt = 0; jt < 2; ++jt)
#pragma unroll
      for (int it = 0; it < 2; ++it)
#pragma unroll
        for (int r = 0; r < 16; ++r) {
          const int j = jt * 32 + (r & 3) + 8 * (r >> 2) + 4 * h5;
          s[jt][it][r] += bT[j * 64 + it * 32 + n];
        }

    // in-lane softmax per i-row (lane pair n, n+32 holds the two j-halves)
#pragma unroll
    for (int it = 0; it < 2; ++it) {
      const int i = it * 32 + n;
      float mx = s[0][it][0];
#pragma unroll
      for (int jt = 0; jt < 2; ++jt)
#pragma unroll
        for (int r = 0; r < 16; ++r) mx = fmaxf(mx, s[jt][it][r]);
      mx = fmaxf(mx, __shfl_xor(mx, 32));
      float sum = 0.f;
#pragma unroll
      for (int jt = 0; jt < 2; ++jt)
#pragma unroll
        for (int r = 0; r < 16; ++r) {
          const float p = __expf(s[jt][it][r] - mx);
          s[jt][it][r] = p;
          sum += p;
        }
      sum += __shfl_xor(sum, 32);
      const float rs = 1.0f / sum;
      const u32 rowoff = (u32)(i * 128);
      const u32 swz = (u32)((i & 7) << 4);
#pragma unroll
      for (int jt = 0; jt < 2; ++jt)
#pragma unroll
        for (int m = 0; m < 8; ++m) {
          const int j = jt * 32 + ((2 * m) & 3) + 8 * (m >> 1) + 4 * h5;
          const u32 off = (rowoff + (u32)(j * 2)) ^ swz;
          *(u32*)((char*)Pw + off) =
              pack2rn(s[jt][it][2 * m] * rs, s[jt][it][2 * m + 1] * rs);
        }
    }

    // PV: O[64i][16d] = P[64x64] . V[64x16]  (16x16x32, N = d = 16 exactly)
    bf16x8 bv[2];
#pragma unroll
    for (int ks = 0; ks < 2; ++ks) {
      union { uint4 u; bf16x8 v; } T;
      T.u = *(const uint4*)&v_sT[hb + il][ks * 32 + jg * 8];
      bv[ks] = T.v;
    }
#pragma unroll
    for (int it2 = 0; it2 < 4; ++it2) {
      f32x4 pv = {0.f, 0.f, 0.f, 0.f};
#pragma unroll
      for (int ks = 0; ks < 2; ++ks) {
        const int i = it2 * 16 + il;
        const u32 off =
            ((u32)(i * 128 + ks * 64 + jg * 16)) ^ ((u32)((i & 7) << 4));
        union { uint4 u; bf16x8 v; } A;
        A.u = *(const uint4*)((const char*)Pw + off);
        pv = __builtin_amdgcn_mfma_f32_16x16x32_bf16(A.v, bv[ks], pv, 0, 0, 0);
      }
#pragma unroll
      for (int rr = 0; rr < 4; ++rr) {
        const int i = it2 * 16 + jg * 4 + rr;
        const int iy = i >> 3, ix = i & 7;
        o_img[(((size_t)(b * H_ + h0 + iy)) * W_ + (w0 + ix)) * C_ + hb + il] =
            f2brn(pv[rr]);
      }
    }
  }
}

// ---------------------------------------------------------------------------
// K2 (MFMA): out1 = ox + oy + bx + by.
// Round 11: r8 base (pad 20, 2 blocks/CU) + pinned async-STAGE split.
// sched_barrier(0) between prefetch-issue and MFMA cluster prevents the
// compiler from sinking the loads (r9 failure). Expect VGPR ~200-230.
// ---------------------------------------------------------------------------
__global__ __launch_bounds__(256, 2) void k_conv2m(
    const u16* __restrict__ o_nhwc, const u16* __restrict__ wt,
    const float* __restrict__ bxg, const float* __restrict__ byg,
    u16* __restrict__ out1)
{
  __shared__ u16 tile[9 * 136 * 20];   // 47.8 KB
  __shared__ float bias_l[128];

  const int tid = threadIdx.x;
  // XCD swizzle: 1024 blocks = 8 XCDs x 128 contiguous ids (bijective)
  const int nb = (blockIdx.x & 7) * 128 + (blockIdx.x >> 3);
  const int wh = nb & 1, oh = (nb >> 1) & 1, hg = (nb >> 2) & 127, b = nb >> 9;
  const int h0 = hg << 1;             // 2 output rows h0, h0+1
  const int ob = oh * 128, wb0 = wh * 128;
  const int lane = tid & 63, wid = tid >> 6;
  const int o64 = (wid & 1) * 64;         // wave M-tile
  const int w64 = ((wid >> 1) & 1) * 64;  // wave N (w) tile
  const int n = lane & 31, h5 = lane >> 5;

  if (tid < 128) bias_l[tid] = bxg[ob + tid] + byg[ob + tid];

  // ---- staging geometry: 1224 cells, 5 per thread (last round partial) ----
  const u16* srcp[5];
  u32 dstoff[5];
#pragma unroll
  for (int k = 0; k < 5; ++k) {
    const int e = tid + (k << 8);
    srcp[k] = nullptr;
    dstoff[k] = 0;
    if (e < 1224) {
      const int r = e / 136, wi = e - r * 136;
      const int hp = h0 - 3 + r;
      const int wp = wb0 + wi - 4;
      dstoff[k] = (u32)((r * 136 + wi) * 20);
      if (hp >= 0 && hp <= 256 && wp >= 0 && wp <= 256) {
        const int hr = (hp == 256) ? 254 : hp;
        const int wr = (wp == 256) ? 254 : wp;
        srcp[k] = o_nhwc + (((size_t)(b * H_ + hr)) * W_ + wr) * C_;
      }
    }
  }

  // prologue: prefetch chunk 0
  uint4 pre[5][2];
#pragma unroll
  for (int k = 0; k < 5; ++k) {
    pre[k][0] = make_uint4(0, 0, 0, 0);
    pre[k][1] = make_uint4(0, 0, 0, 0);
    if (srcp[k]) {
      pre[k][0] = *(const uint4*)(srcp[k]);
      pre[k][1] = *(const uint4*)(srcp[k] + 8);
    }
  }

  f32x16 acc[2][2][2];   // [row][mt][nt]
#pragma unroll
  for (int r2 = 0; r2 < 2; ++r2)
#pragma unroll
    for (int mt = 0; mt < 2; ++mt)
#pragma unroll
      for (int nt = 0; nt < 2; ++nt)
#pragma unroll
        for (int i = 0; i < 16; ++i) acc[r2][mt][nt][i] = 0.f;

  for (int cb = 0; cb < 16; ++cb) {
    const int c0 = cb * 16;
    __syncthreads();   // previous chunk's compute done -> LDS writable
    // ---- write prefetched chunk cb from registers to LDS ----
#pragma unroll
    for (int k = 0; k < 5; ++k) {
      if (tid + (k << 8) < 1224) {
        u16* d = &tile[dstoff[k]];
        *(uint2*)(d)      = make_uint2(pre[k][0].x, pre[k][0].y);
        *(uint2*)(d + 4)  = make_uint2(pre[k][0].z, pre[k][0].w);
        *(uint2*)(d + 8)  = make_uint2(pre[k][1].x, pre[k][1].y);
        *(uint2*)(d + 12) = make_uint2(pre[k][1].z, pre[k][1].w);
      }
    }
    __syncthreads();
    // ---- issue chunk cb+1 loads; PIN with sched_barrier so they cannot
    //      be sunk below the MFMA cluster (r9 failure mode) ----
    if (cb < 15) {
      const int c1 = c0 + 16;
#pragma unroll
      for (int k = 0; k < 5; ++k) {
        pre[k][0] = make_uint4(0, 0, 0, 0);
        pre[k][1] = make_uint4(0, 0, 0, 0);
        if (srcp[k]) {
          pre[k][0] = *(const uint4*)(srcp[k] + c1);
          pre[k][1] = *(const uint4*)(srcp[k] + c1 + 8);
        }
      }
    }
    __builtin_amdgcn_sched_barrier(0);
    // ---- compute: 2 convs x 8 taps, K=16 channels, BOTH rows per wave ----
#pragma unroll
    for (int cv = 0; cv < 2; ++cv) {
      const u16* wbase = wt + (size_t)cv * 524288;
#pragma unroll
      for (int t = 0; t < 8; ++t) {
        bf16x8 a[2];
#pragma unroll
        for (int mt = 0; mt < 2; ++mt) {
          const int o = ob + o64 + mt * 32 + n;
          union { uint4 u; bf16x8 v; } Uu;
          Uu.u = *(const uint4*)(wbase + ((size_t)(t * 256 + o)) * 256 + c0 + h5 * 8);
          a[mt] = Uu.v;
        }
        bf16x8 bb[2][2];   // [row][nt]
#pragma unroll
        for (int r2 = 0; r2 < 2; ++r2)
#pragma unroll
          for (int nt = 0; nt < 2; ++nt) {
            const int rr = cv ? (r2 + 3) : (r2 + t);
            const int wi = w64 + nt * 32 + n + (cv ? (t + 1) : 4);
            const u16* p = &tile[(rr * 136 + wi) * 20 + h5 * 8];
            union { uint2 u[2]; bf16x8 v; } Uu;
            Uu.u[0] = *(const uint2*)p;
            Uu.u[1] = *(const uint2*)(p + 4);
            bb[r2][nt] = Uu.v;
          }
#pragma unroll
        for (int r2 = 0; r2 < 2; ++r2) {
          acc[r2][0][0] = __builtin_amdgcn_mfma_f32_32x32x16_bf16(a[0], bb[r2][0], acc[r2][0][0], 0, 0, 0);
          acc[r2][0][1] = __builtin_amdgcn_mfma_f32_32x32x16_bf16(a[0], bb[r2][1], acc[r2][0][1], 0, 0, 0);
          acc[r2][1][0] = __builtin_amdgcn_mfma_f32_32x32x16_bf16(a[1], bb[r2][0], acc[r2][1][0], 0, 0, 0);
          acc[r2][1][1] = __builtin_amdgcn_mfma_f32_32x32x16_bf16(a[1], bb[r2][1], acc[r2][1][1], 0, 0, 0);
        }
      }
    }
  }
  // ---- epilogue: +bias, bf16, NCHW, both rows ----
#pragma unroll
  for (int r2 = 0; r2 < 2; ++r2)
#pragma unroll
    for (int mt = 0; mt < 2; ++mt)
#pragma unroll
      for (int nt = 0; nt < 2; ++nt)
#pragma unroll
        for (int r = 0; r < 16; ++r) {
          const int om = o64 + mt * 32 + (r & 3) + 8 * (r >> 2) + 4 * h5;
          const int o = ob + om;
          const int wg = wb0 + w64 + nt * 32 + n;
          const float v = acc[r2][mt][nt][r] + bias_l[om];
          out1[(((size_t)(b * C_ + o)) * H_ + (h0 + r2)) * W_ + wg] = f2b(v);
        }
}

// ---------------------------------------------------------------------------
// K3: depthwise 8x8 conv + BN (unchanged).
// ---------------------------------------------------------------------------
__global__ __launch_bounds__(256) void k_dwbn(
    const u16* __restrict__ out1, const float* __restrict__ wdw,
    const float* __restrict__ gam, const float* __restrict__ bet,
    const float* __restrict__ mea, const float* __restrict__ var,
    u16* __restrict__ bno)
{
  __shared__ u16 tile[23][264];
  const int tid = threadIdx.x, nb = blockIdx.x;
  const int c = nb & 255, ht = (nb >> 8) & 15, b = nb >> 12;
  const int h0 = ht * 16;

  for (int e = tid; e < 23 * 264; e += 256) {
    const int tr = e / 264, tc = e % 264;
    const int r = h0 - 3 + tr;
    const int cg = tc - 3;
    u16 v = 0;
    if (r >= 0 && r <= 256 && cg >= 0 && cg <= 256) {
      const int rr = (r == 256) ? 254 : r;
      const int cgm = (cg == 256) ? 254 : cg;
      v = out1[(((size_t)(b * C_ + c)) * H_ + rr) * W_ + cgm];
    }
    tile[tr][tc] = v;
  }
  float wk[64];
#pragma unroll
  for (int k2 = 0; k2 < 64; ++k2) wk[k2] = wdw[c * 64 + k2];
  const float scl = gam[c] / sqrtf(var[c] + 1e-5f);
  const float shf = bet[c] - mea[c] * scl;
  __syncthreads();

  const int wg = tid & 31, hg = tid >> 5;
  const int w0 = wg * 8;
#pragma unroll
  for (int k = 0; k < 2; ++k) {
    const int hl = hg * 2 + k;
    float a[8];
#pragma unroll
    for (int s = 0; s < 8; ++s) a[s] = 0.f;
#pragma unroll
    for (int i = 0; i < 8; ++i) {
      const uint4 va = *(const uint4*)&tile[hl + i][w0];
      const uint4 vb = *(const uint4*)&tile[hl + i][w0 + 8];
      float f[16];
      f[0] = b2f_lo(va.x);  f[1] = b2f_hi(va.x);  f[2] = b2f_lo(va.y);  f[3] = b2f_hi(va.y);
      f[4] = b2f_lo(va.z);  f[5] = b2f_hi(va.z);  f[6] = b2f_lo(va.w);  f[7] = b2f_hi(va.w);
      f[8] = b2f_lo(vb.x);  f[9] = b2f_hi(vb.x);  f[10] = b2f_lo(vb.y); f[11] = b2f_hi(vb.y);
      f[12] = b2f_lo(vb.z); f[13] = b2f_hi(vb.z); f[14] = b2f_lo(vb.w); f[15] = b2f_hi(vb.w);
#pragma unroll
      for (int j = 0; j < 8; ++j) {
        const float wv = wk[i * 8 + j];
#pragma unroll
        for (int s = 0; s < 8; ++s) a[s] += f[s + j] * wv;
      }
    }
    uint4 uv;
    uv.x = pack2(a[0] * scl + shf, a[1] * scl + shf);
    uv.y = pack2(a[2] * scl + shf, a[3] * scl + shf);
    uv.z = pack2(a[4] * scl + shf, a[5] * scl + shf);
    uv.w = pack2(a[6] * scl + shf, a[7] * scl + shf);
    *(uint4*)&bno[(((size_t)(b * C_ + c)) * H_ + h0 + hl) * W_ + w0] = uv;
  }
}

// ---------------------------------------------------------------------------
// K4 (MFMA): 1x1 projection (unchanged). Output f32.
// ---------------------------------------------------------------------------
__global__ __launch_bounds__(256) void k_projm(
    const u16* __restrict__ bn, const float* __restrict__ wp, float* __restrict__ out)
{
  const int tid = threadIdx.x, nb = blockIdx.x;
  const int oh = nb & 1;
  const int pb = nb >> 1;            // 0..1023
  const int b  = pb >> 9;
  const int px0 = (pb & 511) << 7;   // 128-px slab (linear in NCHW plane)
  const int lane = tid & 63, wid = tid >> 6;
  const int wo = (wid >> 1) * 64, wpx = (wid & 1) * 64;
  const int n = lane & 31, h5 = lane >> 5;
  const int ob = oh * 128;
  const int pxl = px0 + wpx + n;

  f32x16 acc[2][2];
#pragma unroll
  for (int mt = 0; mt < 2; ++mt)
#pragma unroll
    for (int nt = 0; nt < 2; ++nt)
#pragma unroll
      for (int i = 0; i < 16; ++i) acc[mt][nt][i] = 0.f;

  const u16* bnb = bn + (size_t)b * C_ * HW_;
#pragma unroll 2
  for (int cb = 0; cb < 16; ++cb) {
    const int c0 = cb * 16;
    bf16x8 a[2];
#pragma unroll
    for (int mt = 0; mt < 2; ++mt) {
      const int row = ob + wo + mt * 32 + n;
      const float4 w0v = *(const float4*)&wp[(size_t)row * 256 + c0 + h5 * 8];
      const float4 w1v = *(const float4*)&wp[(size_t)row * 256 + c0 + h5 * 8 + 4];
      union { u32 u[4]; bf16x8 v; } T;
      T.u[0] = pack2rn(w0v.x, w0v.y);
      T.u[1] = pack2rn(w0v.z, w0v.w);
      T.u[2] = pack2rn(w1v.x, w1v.y);
      T.u[3] = pack2rn(w1v.z, w1v.w);
      a[mt] = T.v;
    }
    bf16x8 bb[2];
#pragma unroll
    for (int nt = 0; nt < 2; ++nt) {
      const u16* sp = bnb + (size_t)(c0 + h5 * 8) * HW_ + (pxl + nt * 32);
      const u32 e0 = sp[0 * HW_], e1 = sp[1 * HW_], e2 = sp[2 * HW_], e3 = sp[3 * HW_];
      const u32 e4 = sp[4 * HW_], e5 = sp[5 * HW_], e6 = sp[6 * HW_], e7 = sp[7 * HW_];
      union { u32 u[4]; bf16x8 v; } T;
      T.u[0] = e0 | (e1 << 16);
      T.u[1] = e2 | (e3 << 16);
      T.u[2] = e4 | (e5 << 16);
      T.u[3] = e6 | (e7 << 16);
      bb[nt] = T.v;
    }
    acc[0][0] = __builtin_amdgcn_mfma_f32_32x32x16_bf16(a[0], bb[0], acc[0][0], 0, 0, 0);
    acc[0][1] = __builtin_amdgcn_mfma_f32_32x32x16_bf16(a[0], bb[1], acc[0][1], 0, 0, 0);
    acc[1][0] = __builtin_amdgcn_mfma_f32_32x32x16_bf16(a[1], bb[0], acc[1][0], 0, 0, 0);
    acc[1][1] = __builtin_amdgcn_mfma_f32_32x32x16_bf16(a[1], bb[1], acc[1][1], 0, 0, 0);
  }
#pragma unroll
  for (int mt = 0; mt < 2; ++mt)
#pragma unroll
    for (int nt = 0; nt < 2; ++nt)
#pragma unroll
      for (int r = 0; r < 16; ++r) {
        const int o = ob + wo + mt * 32 + (r & 3) + 8 * (r >> 2) + 4 * h5;
        out[((size_t)(b * C_ + o)) * HW_ + (pxl + nt * 32)] = acc[mt][nt][r];
      }
}

// ---------------------------------------------------------------------------
extern "C" void kernel_launch(void* const* d_in, const int* in_sizes, int n_in,
                              void* d_out, int out_size, void* d_ws, size_t ws_size,
                              hipStream_t stream)
{
  const float* x     = (const float*)d_in[0];
  const float* wqkv  = (const float*)d_in[1];
  const float* rel   = (const float*)d_in[2];
  const float* wax   = (const float*)d_in[3];
  const float* bax   = (const float*)d_in[4];
  const float* way   = (const float*)d_in[5];
  const float* bay   = (const float*)d_in[6];
  const float* wdw   = (const float*)d_in[7];
  const float* gam   = (const float*)d_in[8];
  const float* bet   = (const float*)d_in[9];
  const float* mea   = (const float*)d_in[10];
  const float* var   = (const float*)d_in[11];
  const float* wproj = (const float*)d_in[12];
  float* out = (float*)d_out;

  const size_t N = (size_t)B_ * C_ * H_ * W_;
  u16* oNHWC  = (u16*)d_out;        // bf16 o, NHWC (first half of f32 out)
  u16* out1b  = (u16*)d_out + N;    // bf16 out1, NCHW (second half)
  u16* wtbuf  = (u16*)d_ws;         // WT 2MB + w8 384KB (bf16)
  float* biasT = (float*)((char*)d_ws + 2490368);  // 256KB, after WT+w8
  u16* bnbuf  = (u16*)d_ws;         // bn NCHW bf16 (reuses region after K2)

  hipLaunchKernelGGL(k_wt,     dim3(256),  dim3(256), 0, stream, wax, way, wqkv, rel, wtbuf, biasT);
  hipLaunchKernelGGL(k_attn,   dim3(2048), dim3(256), 0, stream, x, wtbuf + 1048576, biasT, oNHWC);
  hipLaunchKernelGGL(k_conv2m, dim3(1024), dim3(256), 0, stream, oNHWC, wtbuf, bax, bay, out1b);
  hipLaunchKernelGGL(k_dwbn,   dim3(8192), dim3(256), 0, stream, out1b, wdw, gam, bet, mea, var, bnbuf);
  hipLaunchKernelGGL(k_projm,  dim3(2048), dim3(256), 0, stream, bnbuf, wproj, out);
}

// Round 8
// 981.781 us; speedup vs baseline: 1.4754x; 1.0002x over previous
//
#include <hip/hip_runtime.h>
#include <stdint.h>

// GlobalAttention fused pipeline, MI355X gfx950.
// Round 12: k_conv2m rebuilt on global_load_lds + double-buffered LDS.
// r9/r11 lesson: register-carried prefetch is always sunk by the allocator
// (VGPR stayed 128 twice). gload_lds has no dest VGPR -> cannot be sunk.
// LDS reshaped to [buf][h5-plane][cell*16B] so the wave-uniform-base+lane*16
// write rule (m104) matches the staging order; reads stay ds_read_b128.
// OOB/reflect cells pre-zeroed once (chunk-invariant), exec-masked DMA.
//   K0: wx,wy -> WT bf16; wqkv -> w8 bf16 [768][256]; rel -> biasT[16][64][64] f32
//   K1: x -> xb LDS once; MFMA qkv GEMM (head-remapped); per-wave attention
//   K2: o,WT -> out1 NCHW bf16 [MFMA, dbuf gload_lds pipeline]
//   K3: out1 -> bn NCHW bf16 @ d_ws
//   K4: bn -> d_out f32 final [MFMA]

#define B_ 2
#define C_ 256
#define H_ 256
#define W_ 256
#define HW_ 65536

typedef unsigned short u16;
typedef unsigned int u32;
typedef short bf16x8 __attribute__((ext_vector_type(8)));
typedef float f32x4 __attribute__((ext_vector_type(4)));
typedef float f32x16 __attribute__((ext_vector_type(16)));

__device__ __forceinline__ float b2f(u16 h) {
  union { u32 u; float f; } x; x.u = ((u32)h) << 16; return x.f;
}
__device__ __forceinline__ float b2f_lo(u32 u) {
  union { u32 v; float f; } x; x.v = u << 16; return x.f;
}
__device__ __forceinline__ float b2f_hi(u32 u) {
  union { u32 v; float f; } x; x.v = u & 0xffff0000u; return x.f;
}
__device__ __forceinline__ u16 f2b(float f) {  // RNE
  union { float f; u32 u; } x; x.f = f;
  return (u16)((x.u + 0x7fffu + ((x.u >> 16) & 1u)) >> 16);
}
__device__ __forceinline__ u32 pack2(float a, float b) {
  return (u32)f2b(a) | ((u32)f2b(b) << 16);
}
// fast round-half-up bf16 pack: 3 ops via v_perm
__device__ __forceinline__ u32 pack2rn(float a, float b) {
  u32 ua = __float_as_uint(a) + 0x8000u;
  u32 ub = __float_as_uint(b) + 0x8000u;
  return __builtin_amdgcn_perm(ub, ua, 0x07060302u);
}
__device__ __forceinline__ u16 f2brn(float f) {
  return (u16)((__float_as_uint(f) + 0x8000u) >> 16);
}

// async 16B global -> LDS DMA (writes wave-uniform base + lane*16)
__device__ __forceinline__ void gl_lds16(const u16* g, u16* l) {
  __builtin_amdgcn_global_load_lds(
      (const __attribute__((address_space(1))) u32*)(const void*)g,
      (__attribute__((address_space(3))) u32*)l, 16, 0, 0);
}

// ---------------------------------------------------------------------------
// K0: WT bf16 [conv][t][o][c]; wqkv -> w8 bf16 [768][256];
//     rel -> biasT[head][j][i] f32 (16*64*64)
// ---------------------------------------------------------------------------
__global__ __launch_bounds__(256) void k_wt(
    const float* __restrict__ wx, const float* __restrict__ wy,
    const float* __restrict__ wqkv, const float* __restrict__ rel,
    u16* __restrict__ wt, float* __restrict__ biasT)
{
  const int o = blockIdx.x, c = threadIdx.x;
  const float* px = wx + ((size_t)o * 256 + c) * 8;
  const float* py = wy + ((size_t)o * 256 + c) * 8;
#pragma unroll
  for (int t = 0; t < 8; ++t) {
    wt[(size_t)t * 65536 + o * 256 + c]          = f2b(px[t]);
    wt[524288 + (size_t)t * 65536 + o * 256 + c] = f2b(py[t]);
  }
  u16* w8 = wt + 1048576;
#pragma unroll
  for (int t = 0; t < 3; ++t) {
    const int row = o + t * 256;
    w8[(size_t)row * 256 + c] = f2b(wqkv[(size_t)row * 256 + c]);
  }
  // biasT[h][j][i] = rel[ridx(i,j)*16+h]
  const int flat = o * 256 + c;
  const int h = flat >> 12, j = (flat >> 6) & 63, i = flat & 63;
  const int iy = i >> 3, ix = i & 7, jy = j >> 3, jx = j & 7;
  const int ridx = (iy - jy + 7) * 15 + (ix - jx + 7);
  biasT[flat] = rel[ridx * 16 + h];
}

// ---------------------------------------------------------------------------
// K1: qkv (MFMA) + windowed attention (per-wave, barrier-free phase 3).
// Wave w owns heads 4w..4w+3 (q/k/v channels 64w..64w+63).
// ---------------------------------------------------------------------------
__global__ __launch_bounds__(256) void k_attn(
    const float* __restrict__ x, const u16* __restrict__ w8,
    const float* __restrict__ biasT, u16* __restrict__ o_img)
{
  __shared__ __align__(16) union {
    u16 xb[64][264];   // phase 1-2: x window [px][c] bf16
    u16 P[4][4096];    // phase 3: per-wave P tile [i][j], XOR-swizzled
  } U;
  __shared__ __align__(16) u16 q_s[64][264];   // [px][ch], q pre-scaled 0.25
  __shared__ __align__(16) u16 k_s[64][264];   // [px][ch]
  __shared__ __align__(16) u16 v_sT[256][72];  // [ch][px]

  const int tid = threadIdx.x;
  const int nb  = blockIdx.x;
  const int b   = nb >> 10;
  const int hh  = (nb >> 5) & 31;
  const int ww  = nb & 31;
  const int h0  = hh << 3, w0 = ww << 3;

  // ---- phase 1: stage x window -> xb [px][c] bf16 ----
  {
    const int c2 = tid & 127;
    const int half = tid >> 7;
    const float* p0 = x + (((size_t)(b * C_ + 2 * c2)) * H_ + (h0 + half * 4)) * W_ + w0;
    const float* p1 = p0 + (size_t)H_ * W_;
#pragma unroll
    for (int r = 0; r < 4; ++r) {
      const float4 a0 = *(const float4*)(p0 + r * W_);
      const float4 a1 = *(const float4*)(p0 + r * W_ + 4);
      const float4 b0 = *(const float4*)(p1 + r * W_);
      const float4 b1 = *(const float4*)(p1 + r * W_ + 4);
      const float fa[8] = {a0.x, a0.y, a0.z, a0.w, a1.x, a1.y, a1.z, a1.w};
      const float fb[8] = {b0.x, b0.y, b0.z, b0.w, b1.x, b1.y, b1.z, b1.w};
      const int px0 = (half * 4 + r) * 8;
#pragma unroll
      for (int cc = 0; cc < 8; ++cc)
        *(u32*)&U.xb[px0 + cc][2 * c2] = pack2rn(fa[cc], fb[cc]);
    }
  }
  __syncthreads();

  // ---- phase 2: MFMA GEMM, wave w computes rows for its own heads ----
  const int lane = tid & 63, wid = tid >> 6;
  const int n = lane & 31, h5 = lane >> 5;

  f32x16 acc[6][2];
#pragma unroll
  for (int mt = 0; mt < 6; ++mt)
#pragma unroll
    for (int nt = 0; nt < 2; ++nt)
#pragma unroll
      for (int i = 0; i < 16; ++i) acc[mt][nt][i] = 0.f;

#pragma unroll 2
  for (int kb = 0; kb < 16; ++kb) {
    const int k0 = kb * 16;
    bf16x8 bfr[2];
#pragma unroll
    for (int nt = 0; nt < 2; ++nt) {
      union { uint4 u; bf16x8 v; } T;
      T.u = *(const uint4*)&U.xb[nt * 32 + n][k0 + h5 * 8];
      bfr[nt] = T.v;
    }
#pragma unroll
    for (int mt = 0; mt < 6; ++mt) {
      // q rows: wid*64.., k rows: 256+wid*64.., v rows: 512+wid*64..
      const int row = (mt >> 1) * 256 + wid * 64 + (mt & 1) * 32 + n;
      union { uint4 u; bf16x8 v; } A;
      A.u = *(const uint4*)(w8 + (size_t)row * 256 + k0 + h5 * 8);
      acc[mt][0] = __builtin_amdgcn_mfma_f32_32x32x16_bf16(A.v, bfr[0], acc[mt][0], 0, 0, 0);
      acc[mt][1] = __builtin_amdgcn_mfma_f32_32x32x16_bf16(A.v, bfr[1], acc[mt][1], 0, 0, 0);
    }
  }

  // ---- phase 2.5: scatter q,k -> [px][ch] (u32 pairs); v -> [ch][px] ----
  const int chb0 = wid * 64 + 4 * h5;
#pragma unroll
  for (int mt = 0; mt < 4; ++mt) {
    u16 (*dst)[264] = (mt < 2) ? q_s : k_s;
    const float qs = (mt < 2) ? 0.25f : 1.0f;
    const int chb = chb0 + (mt & 1) * 32;
#pragma unroll
    for (int nt = 0; nt < 2; ++nt) {
      const int px = nt * 32 + n;
#pragma unroll
      for (int m = 0; m < 8; ++m) {
        const int ch = chb + ((2 * m) & 3) + 8 * (m >> 1);
        *(u32*)&dst[px][ch] =
            pack2rn(acc[mt][nt][2 * m] * qs, acc[mt][nt][2 * m + 1] * qs);
      }
    }
  }
#pragma unroll
  for (int mt = 4; mt < 6; ++mt) {
    const int chb = chb0 + (mt & 1) * 32;
#pragma unroll
    for (int nt = 0; nt < 2; ++nt) {
      const int px = nt * 32 + n;
#pragma unroll
      for (int r = 0; r < 16; ++r) {
        const int ch = chb + (r & 3) + 8 * (r >> 2);
        v_sT[ch][px] = f2brn(acc[mt][nt][r]);
      }
    }
  }
  __syncthreads();  // protect xb->P union across all waves

  // ---- phase 3: per-wave attention, 4 heads, no barriers ----
  u16* Pw = U.P[wid];
  const int il = lane & 15, jg = lane >> 4;

  for (int hl = 0; hl < 4; ++hl) {
    const int head = wid * 4 + hl;
    const int hb = head * 16;

    // QK^T swapped: S^T[j][i] = K[j][d] . Q^T[d][i]   (scale folded into q)
    bf16x8 ak[2], bq[2];
#pragma unroll
    for (int jt = 0; jt < 2; ++jt) {
      union { uint4 u; bf16x8 v; } T;
      T.u = *(const uint4*)&k_s[jt * 32 + n][hb + h5 * 8];
      ak[jt] = T.v;
    }
#pragma unroll
    for (int it = 0; it < 2; ++it) {
      union { uint4 u; bf16x8 v; } T;
      T.u = *(const uint4*)&q_s[it * 32 + n][hb + h5 * 8];
      bq[it] = T.v;
    }
    f32x16 zro;
#pragma unroll
    for (int e = 0; e < 16; ++e) zro[e] = 0.f;
    f32x16 s[2][2];
#pragma unroll
    for (int jt = 0; jt < 2; ++jt)
#pragma unroll
      for (int it = 0; it < 2; ++it)
        s[jt][it] = __builtin_amdgcn_mfma_f32_32x32x16_bf16(ak[jt], bq[it], zro, 0, 0, 0);

    // + bias (biasT[head][j][i], coalesced over i = lanes)
    const float* bT = biasT + head * 4096;
#pragma unroll
    for (int jt = 0; jt < 2; ++jt)
#pragma unroll
      for (int it = 0; it < 2; ++it)
#pragma unroll
        for (int r = 0; r < 16; ++r) {
          const int j = jt * 32 + (r & 3) + 8 * (r >> 2) + 4 * h5;
          s[jt][it][r] += bT[j * 64 + it * 32 + n];
        }

    // in-lane softmax per i-row (lane pair n, n+32 holds the two j-halves)
#pragma unroll
    for (int it = 0; it < 2; ++it) {
      const int i = it * 32 + n;
      float mx = s[0][it][0];
#pragma unroll
      for (int jt = 0; jt < 2; ++jt)
#pragma unroll
        for (int r = 0; r < 16; ++r) mx = fmaxf(mx, s[jt][it][r]);
      mx = fmaxf(mx, __shfl_xor(mx, 32));
      float sum = 0.f;
#pragma unroll
      for (int jt = 0; jt < 2; ++jt)
#pragma unroll
        for (int r = 0; r < 16; ++r) {
          const float p = __expf(s[jt][it][r] - mx);
          s[jt][it][r] = p;
          sum += p;
        }
      sum += __shfl_xor(sum, 32);
      const float rs = 1.0f / sum;
      const u32 rowoff = (u32)(i * 128);
      const u32 swz = (u32)((i & 7) << 4);
#pragma unroll
      for (int jt = 0; jt < 2; ++jt)
#pragma unroll
        for (int m = 0; m < 8; ++m) {
          const int j = jt * 32 + ((2 * m) & 3) + 8 * (m >> 1) + 4 * h5;
          const u32 off = (rowoff + (u32)(j * 2)) ^ swz;
          *(u32*)((char*)Pw + off) =
              pack2rn(s[jt][it][2 * m] * rs, s[jt][it][2 * m + 1] * rs);
        }
    }

    // PV: O[64i][16d] = P[64x64] . V[64x16]  (16x16x32, N = d = 16 exactly)
    bf16x8 bv[2];
#pragma unroll
    for (int ks = 0; ks < 2; ++ks) {
      union { uint4 u; bf16x8 v; } T;
      T.u = *(const uint4*)&v_sT[hb + il][ks * 32 + jg * 8];
      bv[ks] = T.v;
    }
#pragma unroll
    for (int it2 = 0; it2 < 4; ++it2) {
      f32x4 pv = {0.f, 0.f, 0.f, 0.f};
#pragma unroll
      for (int ks = 0; ks < 2; ++ks) {
        const int i = it2 * 16 + il;
        const u32 off =
            ((u32)(i * 128 + ks * 64 + jg * 16)) ^ ((u32)((i & 7) << 4));
        union { uint4 u; bf16x8 v; } A;
        A.u = *(const uint4*)((const char*)Pw + off);
        pv = __builtin_amdgcn_mfma_f32_16x16x32_bf16(A.v, bv[ks], pv, 0, 0, 0);
      }
#pragma unroll
      for (int rr = 0; rr < 4; ++rr) {
        const int i = it2 * 16 + jg * 4 + rr;
        const int iy = i >> 3, ix = i & 7;
        o_img[(((size_t)(b * H_ + h0 + iy)) * W_ + (w0 + ix)) * C_ + hb + il] =
            f2brn(pv[rr]);
      }
    }
  }
}

// ---------------------------------------------------------------------------
// K2 (MFMA): out1 = ox + oy + bx + by.
// Round 12: double-buffered gload_lds pipeline.
// LDS: tile[buf][plane(h5)][cell*8 u16], cell = rr*136+wi (16B units).
// Staging cell e = tid + k*256 -> LDS off (k*256+wid*64)*16 + lane*16:
// wave-uniform base + lane*16 == the gload_lds HW write pattern (m104).
// OOB cells chunk-invariant -> pre-zeroed once; DMA exec-masked by srcp.
// One barrier per chunk; stage latency hidden under the MFMA cluster.
// ---------------------------------------------------------------------------
__global__ __launch_bounds__(256, 2) void k_conv2m(
    const u16* __restrict__ o_nhwc, const u16* __restrict__ wt,
    const float* __restrict__ bxg, const float* __restrict__ byg,
    u16* __restrict__ out1)
{
  __shared__ u16 tile[2][2][1224 * 8];   // 78336 B
  __shared__ float bias_l[128];

  const int tid = threadIdx.x;
  // XCD swizzle: 1024 blocks = 8 XCDs x 128 contiguous ids (bijective)
  const int nb = (blockIdx.x & 7) * 128 + (blockIdx.x >> 3);
  const int wh = nb & 1, oh = (nb >> 1) & 1, hg = (nb >> 2) & 127, b = nb >> 9;
  const int h0 = hg << 1;             // 2 output rows h0, h0+1
  const int ob = oh * 128, wb0 = wh * 128;
  const int lane = tid & 63, wid = tid >> 6;
  const int o64 = (wid & 1) * 64;         // wave M-tile
  const int w64 = ((wid >> 1) & 1) * 64;  // wave N (w) tile
  const int n = lane & 31, h5 = lane >> 5;

  if (tid < 128) bias_l[tid] = bxg[ob + tid] + byg[ob + tid];

  // ---- per-lane staging source (reflect-clamped); cell e = tid + k*256 ----
  const u16* srcp[5];
#pragma unroll
  for (int k = 0; k < 5; ++k) {
    const int e = tid + (k << 8);
    srcp[k] = nullptr;
    if (e < 1224) {
      const int r = e / 136, wi = e - r * 136;
      const int hp = h0 - 3 + r;
      const int wp = wb0 + wi - 4;
      if (hp >= 0 && hp <= 256 && wp >= 0 && wp <= 256) {
        const int hr = (hp == 256) ? 254 : hp;
        const int wr = (wp == 256) ? 254 : wp;
        srcp[k] = o_nhwc + (((size_t)(b * H_ + hr)) * W_ + wr) * C_;
      }
    }
  }

  // ---- zero OOB cells once (chunk-invariant; both buffers, both planes) ----
#pragma unroll
  for (int k = 0; k < 5; ++k) {
    const int e = tid + (k << 8);
    if (e < 1224 && srcp[k] == nullptr) {
      const uint4 z = make_uint4(0, 0, 0, 0);
      *(uint4*)&tile[0][0][e * 8] = z;
      *(uint4*)&tile[0][1][e * 8] = z;
      *(uint4*)&tile[1][0][e * 8] = z;
      *(uint4*)&tile[1][1][e * 8] = z;
    }
  }

  // ---- async stage of one 16-channel chunk into buffer `buf` ----
  auto stage = [&](int buf, int c0) {
#pragma unroll
    for (int k = 0; k < 5; ++k) {
      const int e = tid + (k << 8);
      // wave-uniform LDS bases for this wave's 64-cell span
      u16* l0 = &tile[buf][0][(size_t)(k * 256 + wid * 64) * 8];
      u16* l1 = &tile[buf][1][(size_t)(k * 256 + wid * 64) * 8];
      if (e < 1224 && srcp[k]) {
        gl_lds16(srcp[k] + c0,     l0);
        gl_lds16(srcp[k] + c0 + 8, l1);
      }
    }
  };

  f32x16 acc[2][2][2];   // [row][mt][nt]
#pragma unroll
  for (int r2 = 0; r2 < 2; ++r2)
#pragma unroll
    for (int mt = 0; mt < 2; ++mt)
#pragma unroll
      for (int nt = 0; nt < 2; ++nt)
#pragma unroll
        for (int i = 0; i < 16; ++i) acc[r2][mt][nt][i] = 0.f;

  // prologue: stage chunk 0
  stage(0, 0);
  __syncthreads();   // vmcnt(0) drained by compiler before barrier

  int cur = 0;
  for (int cb = 0; cb < 16; ++cb) {
    const int c0 = cb * 16;
    // issue next chunk's DMA (cannot be sunk -- no dest VGPR)
    if (cb < 15) stage(cur ^ 1, c0 + 16);
    // ---- compute: 2 convs x 8 taps, K=16 channels, BOTH rows per wave ----
#pragma unroll
    for (int cv = 0; cv < 2; ++cv) {
      const u16* wbase = wt + (size_t)cv * 524288;
#pragma unroll
      for (int t = 0; t < 8; ++t) {
        bf16x8 a[2];
#pragma unroll
        for (int mt = 0; mt < 2; ++mt) {
          const int o = ob + o64 + mt * 32 + n;
          union { uint4 u; bf16x8 v; } Uu;
          Uu.u = *(const uint4*)(wbase + ((size_t)(t * 256 + o)) * 256 + c0 + h5 * 8);
          a[mt] = Uu.v;
        }
        bf16x8 bb[2][2];   // [row][nt]
#pragma unroll
        for (int r2 = 0; r2 < 2; ++r2)
#pragma unroll
          for (int nt = 0; nt < 2; ++nt) {
            const int rr = cv ? (r2 + 3) : (r2 + t);
            const int wi = w64 + nt * 32 + n + (cv ? (t + 1) : 4);
            union { uint4 u; bf16x8 v; } Uu;
            Uu.u = *(const uint4*)&tile[cur][h5][(size_t)(rr * 136 + wi) * 8];
            bb[r2][nt] = Uu.v;
          }
#pragma unroll
        for (int r2 = 0; r2 < 2; ++r2) {
          acc[r2][0][0] = __builtin_amdgcn_mfma_f32_32x32x16_bf16(a[0], bb[r2][0], acc[r2][0][0], 0, 0, 0);
          acc[r2][0][1] = __builtin_amdgcn_mfma_f32_32x32x16_bf16(a[0], bb[r2][1], acc[r2][0][1], 0, 0, 0);
          acc[r2][1][0] = __builtin_amdgcn_mfma_f32_32x32x16_bf16(a[1], bb[r2][0], acc[r2][1][0], 0, 0, 0);
          acc[r2][1][1] = __builtin_amdgcn_mfma_f32_32x32x16_bf16(a[1], bb[r2][1], acc[r2][1][1], 0, 0, 0);
        }
      }
    }
    __syncthreads();   // drains DMA vmcnt + syncs; next buf ready
    cur ^= 1;
  }
  // ---- epilogue: +bias, bf16, NCHW, both rows ----
#pragma unroll
  for (int r2 = 0; r2 < 2; ++r2)
#pragma unroll
    for (int mt = 0; mt < 2; ++mt)
#pragma unroll
      for (int nt = 0; nt < 2; ++nt)
#pragma unroll
        for (int r = 0; r < 16; ++r) {
          const int om = o64 + mt * 32 + (r & 3) + 8 * (r >> 2) + 4 * h5;
          const int o = ob + om;
          const int wg = wb0 + w64 + nt * 32 + n;
          const float v = acc[r2][mt][nt][r] + bias_l[om];
          out1[(((size_t)(b * C_ + o)) * H_ + (h0 + r2)) * W_ + wg] = f2b(v);
        }
}

// ---------------------------------------------------------------------------
// K3: depthwise 8x8 conv + BN (unchanged).
// ---------------------------------------------------------------------------
__global__ __launch_bounds__(256) void k_dwbn(
    const u16* __restrict__ out1, const float* __restrict__ wdw,
    const float* __restrict__ gam, const float* __restrict__ bet,
    const float* __restrict__ mea, const float* __restrict__ var,
    u16* __restrict__ bno)
{
  __shared__ u16 tile[23][264];
  const int tid = threadIdx.x, nb = blockIdx.x;
  const int c = nb & 255, ht = (nb >> 8) & 15, b = nb >> 12;
  const int h0 = ht * 16;

  for (int e = tid; e < 23 * 264; e += 256) {
    const int tr = e / 264, tc = e % 264;
    const int r = h0 - 3 + tr;
    const int cg = tc - 3;
    u16 v = 0;
    if (r >= 0 && r <= 256 && cg >= 0 && cg <= 256) {
      const int rr = (r == 256) ? 254 : r;
      const int cgm = (cg == 256) ? 254 : cg;
      v = out1[(((size_t)(b * C_ + c)) * H_ + rr) * W_ + cgm];
    }
    tile[tr][tc] = v;
  }
  float wk[64];
#pragma unroll
  for (int k2 = 0; k2 < 64; ++k2) wk[k2] = wdw[c * 64 + k2];
  const float scl = gam[c] / sqrtf(var[c] + 1e-5f);
  const float shf = bet[c] - mea[c] * scl;
  __syncthreads();

  const int wg = tid & 31, hg = tid >> 5;
  const int w0 = wg * 8;
#pragma unroll
  for (int k = 0; k < 2; ++k) {
    const int hl = hg * 2 + k;
    float a[8];
#pragma unroll
    for (int s = 0; s < 8; ++s) a[s] = 0.f;
#pragma unroll
    for (int i = 0; i < 8; ++i) {
      const uint4 va = *(const uint4*)&tile[hl + i][w0];
      const uint4 vb = *(const uint4*)&tile[hl + i][w0 + 8];
      float f[16];
      f[0] = b2f_lo(va.x);  f[1] = b2f_hi(va.x);  f[2] = b2f_lo(va.y);  f[3] = b2f_hi(va.y);
      f[4] = b2f_lo(va.z);  f[5] = b2f_hi(va.z);  f[6] = b2f_lo(va.w);  f[7] = b2f_hi(va.w);
      f[8] = b2f_lo(vb.x);  f[9] = b2f_hi(vb.x);  f[10] = b2f_lo(vb.y); f[11] = b2f_hi(vb.y);
      f[12] = b2f_lo(vb.z); f[13] = b2f_hi(vb.z); f[14] = b2f_lo(vb.w); f[15] = b2f_hi(vb.w);
#pragma unroll
      for (int j = 0; j < 8; ++j) {
        const float wv = wk[i * 8 + j];
#pragma unroll
        for (int s = 0; s < 8; ++s) a[s] += f[s + j] * wv;
      }
    }
    uint4 uv;
    uv.x = pack2(a[0] * scl + shf, a[1] * scl + shf);
    uv.y = pack2(a[2] * scl + shf, a[3] * scl + shf);
    uv.z = pack2(a[4] * scl + shf, a[5] * scl + shf);
    uv.w = pack2(a[6] * scl + shf, a[7] * scl + shf);
    *(uint4*)&bno[(((size_t)(b * C_ + c)) * H_ + h0 + hl) * W_ + w0] = uv;
  }
}

// ---------------------------------------------------------------------------
// K4 (MFMA): 1x1 projection (unchanged). Output f32.
// ---------------------------------------------------------------------------
__global__ __launch_bounds__(256) void k_projm(
    const u16* __restrict__ bn, const float* __restrict__ wp, float* __restrict__ out)
{
  const int tid = threadIdx.x, nb = blockIdx.x;
  const int oh = nb & 1;
  const int pb = nb >> 1;            // 0..1023
  const int b  = pb >> 9;
  const int px0 = (pb & 511) << 7;   // 128-px slab (linear in NCHW plane)
  const int lane = tid & 63, wid = tid >> 6;
  const int wo = (wid >> 1) * 64, wpx = (wid & 1) * 64;
  const int n = lane & 31, h5 = lane >> 5;
  const int ob = oh * 128;
  const int pxl = px0 + wpx + n;

  f32x16 acc[2][2];
#pragma unroll
  for (int mt = 0; mt < 2; ++mt)
#pragma unroll
    for (int nt = 0; nt < 2; ++nt)
#pragma unroll
      for (int i = 0; i < 16; ++i) acc[mt][nt][i] = 0.f;

  const u16* bnb = bn + (size_t)b * C_ * HW_;
#pragma unroll 2
  for (int cb = 0; cb < 16; ++cb) {
    const int c0 = cb * 16;
    bf16x8 a[2];
#pragma unroll
    for (int mt = 0; mt < 2; ++mt) {
      const int row = ob + wo + mt * 32 + n;
      const float4 w0v = *(const float4*)&wp[(size_t)row * 256 + c0 + h5 * 8];
      const float4 w1v = *(const float4*)&wp[(size_t)row * 256 + c0 + h5 * 8 + 4];
      union { u32 u[4]; bf16x8 v; } T;
      T.u[0] = pack2rn(w0v.x, w0v.y);
      T.u[1] = pack2rn(w0v.z, w0v.w);
      T.u[2] = pack2rn(w1v.x, w1v.y);
      T.u[3] = pack2rn(w1v.z, w1v.w);
      a[mt] = T.v;
    }
    bf16x8 bb[2];
#pragma unroll
    for (int nt = 0; nt < 2; ++nt) {
      const u16* sp = bnb + (size_t)(c0 + h5 * 8) * HW_ + (pxl + nt * 32);
      const u32 e0 = sp[0 * HW_], e1 = sp[1 * HW_], e2 = sp[2 * HW_], e3 = sp[3 * HW_];
      const u32 e4 = sp[4 * HW_], e5 = sp[5 * HW_], e6 = sp[6 * HW_], e7 = sp[7 * HW_];
      union { u32 u[4]; bf16x8 v; } T;
      T.u[0] = e0 | (e1 << 16);
      T.u[1] = e2 | (e3 << 16);
      T.u[2] = e4 | (e5 << 16);
      T.u[3] = e6 | (e7 << 16);
      bb[nt] = T.v;
    }
    acc[0][0] = __builtin_amdgcn_mfma_f32_32x32x16_bf16(a[0], bb[0], acc[0][0], 0, 0, 0);
    acc[0][1] = __builtin_amdgcn_mfma_f32_32x32x16_bf16(a[0], bb[1], acc[0][1], 0, 0, 0);
    acc[1][0] = __builtin_amdgcn_mfma_f32_32x32x16_bf16(a[1], bb[0], acc[1][0], 0, 0, 0);
    acc[1][1] = __builtin_amdgcn_mfma_f32_32x32x16_bf16(a[1], bb[1], acc[1][1], 0, 0, 0);
  }
#pragma unroll
  for (int mt = 0; mt < 2; ++mt)
#pragma unroll
    for (int nt = 0; nt < 2; ++nt)
#pragma unroll
      for (int r = 0; r < 16; ++r) {
        const int o = ob + wo + mt * 32 + (r & 3) + 8 * (r >> 2) + 4 * h5;
        out[((size_t)(b * C_ + o)) * HW_ + (pxl + nt * 32)] = acc[mt][nt][r];
      }
}

// ---------------------------------------------------------------------------
extern "C" void kernel_launch(void* const* d_in, const int* in_sizes, int n_in,
                              void* d_out, int out_size, void* d_ws, size_t ws_size,
                              hipStream_t stream)
{
  const float* x     = (const float*)d_in[0];
  const float* wqkv  = (const float*)d_in[1];
  const float* rel   = (const float*)d_in[2];
  const float* wax   = (const float*)d_in[3];
  const float* bax   = (const float*)d_in[4];
  const float* way   = (const float*)d_in[5];
  const float* bay   = (const float*)d_in[6];
  const float* wdw   = (const float*)d_in[7];
  const float* gam   = (const float*)d_in[8];
  const float* bet   = (const float*)d_in[9];
  const float* mea   = (const float*)d_in[10];
  const float* var   = (const float*)d_in[11];
  const float* wproj = (const float*)d_in[12];
  float* out = (float*)d_out;

  const size_t N = (size_t)B_ * C_ * H_ * W_;
  u16* oNHWC  = (u16*)d_out;        // bf16 o, NHWC (first half of f32 out)
  u16* out1b  = (u16*)d_out + N;    // bf16 out1, NCHW (second half)
  u16* wtbuf  = (u16*)d_ws;         // WT 2MB + w8 384KB (bf16)
  float* biasT = (float*)((char*)d_ws + 2490368);  // 256KB, after WT+w8
  u16* bnbuf  = (u16*)d_ws;         // bn NCHW bf16 (reuses region after K2)

  hipLaunchKernelGGL(k_wt,     dim3(256),  dim3(256), 0, stream, wax, way, wqkv, rel, wtbuf, biasT);
  hipLaunchKernelGGL(k_attn,   dim3(2048), dim3(256), 0, stream, x, wtbuf + 1048576, biasT, oNHWC);
  hipLaunchKernelGGL(k_conv2m, dim3(1024), dim3(256), 0, stream, oNHWC, wtbuf, bax, bay, out1b);
  hipLaunchKernelGGL(k_dwbn,   dim3(8192), dim3(256), 0, stream, out1b, wdw, gam, bet, mea, var, bnbuf);
  hipLaunchKernelGGL(k_projm,  dim3(2048), dim3(256), 0, stream, bnbuf, wproj, out);
}

// Round 9
// 933.544 us; speedup vs baseline: 1.5517x; 1.0517x over previous
//
#include <hip/hip_runtime.h>
#include <stdint.h>

// GlobalAttention fused pipeline, MI355X gfx950.
// Round 13: k_conv2m max-ILP config -- 4 output rows per wave, 256 AGPR acc,
// 1 block/CU (launch_bounds(256,1) -> 512-VGPR budget), A-fragment reuse 8x,
// r12 gload_lds double-buffer kept (essential at 1 block/CU).
// Evidence: r9/r11/r12 staging pipelines all null at 385us -> limiter is the
// per-wave A-load/MFMA chain at full register file; only ILP moves it (r8).
//   K0: wx,wy -> WT bf16; wqkv -> w8 bf16 [768][256]; rel -> biasT[16][64][64] f32
//   K1: x -> xb LDS once; MFMA qkv GEMM (head-remapped); per-wave attention
//   K2: o,WT -> out1 NCHW bf16 [MFMA, 4 rows/block, dbuf DMA]
//   K3: out1 -> bn NCHW bf16 @ d_ws
//   K4: bn -> d_out f32 final [MFMA]

#define B_ 2
#define C_ 256
#define H_ 256
#define W_ 256
#define HW_ 65536

typedef unsigned short u16;
typedef unsigned int u32;
typedef short bf16x8 __attribute__((ext_vector_type(8)));
typedef float f32x4 __attribute__((ext_vector_type(4)));
typedef float f32x16 __attribute__((ext_vector_type(16)));

__device__ __forceinline__ float b2f(u16 h) {
  union { u32 u; float f; } x; x.u = ((u32)h) << 16; return x.f;
}
__device__ __forceinline__ float b2f_lo(u32 u) {
  union { u32 v; float f; } x; x.v = u << 16; return x.f;
}
__device__ __forceinline__ float b2f_hi(u32 u) {
  union { u32 v; float f; } x; x.v = u & 0xffff0000u; return x.f;
}
__device__ __forceinline__ u16 f2b(float f) {  // RNE
  union { float f; u32 u; } x; x.f = f;
  return (u16)((x.u + 0x7fffu + ((x.u >> 16) & 1u)) >> 16);
}
__device__ __forceinline__ u32 pack2(float a, float b) {
  return (u32)f2b(a) | ((u32)f2b(b) << 16);
}
// fast round-half-up bf16 pack: 3 ops via v_perm
__device__ __forceinline__ u32 pack2rn(float a, float b) {
  u32 ua = __float_as_uint(a) + 0x8000u;
  u32 ub = __float_as_uint(b) + 0x8000u;
  return __builtin_amdgcn_perm(ub, ua, 0x07060302u);
}
__device__ __forceinline__ u16 f2brn(float f) {
  return (u16)((__float_as_uint(f) + 0x8000u) >> 16);
}

// async 16B global -> LDS DMA (writes wave-uniform base + lane*16)
__device__ __forceinline__ void gl_lds16(const u16* g, u16* l) {
  __builtin_amdgcn_global_load_lds(
      (const __attribute__((address_space(1))) u32*)(const void*)g,
      (__attribute__((address_space(3))) u32*)l, 16, 0, 0);
}

// ---------------------------------------------------------------------------
// K0: WT bf16 [conv][t][o][c]; wqkv -> w8 bf16 [768][256];
//     rel -> biasT[head][j][i] f32 (16*64*64)
// ---------------------------------------------------------------------------
__global__ __launch_bounds__(256) void k_wt(
    const float* __restrict__ wx, const float* __restrict__ wy,
    const float* __restrict__ wqkv, const float* __restrict__ rel,
    u16* __restrict__ wt, float* __restrict__ biasT)
{
  const int o = blockIdx.x, c = threadIdx.x;
  const float* px = wx + ((size_t)o * 256 + c) * 8;
  const float* py = wy + ((size_t)o * 256 + c) * 8;
#pragma unroll
  for (int t = 0; t < 8; ++t) {
    wt[(size_t)t * 65536 + o * 256 + c]          = f2b(px[t]);
    wt[524288 + (size_t)t * 65536 + o * 256 + c] = f2b(py[t]);
  }
  u16* w8 = wt + 1048576;
#pragma unroll
  for (int t = 0; t < 3; ++t) {
    const int row = o + t * 256;
    w8[(size_t)row * 256 + c] = f2b(wqkv[(size_t)row * 256 + c]);
  }
  // biasT[h][j][i] = rel[ridx(i,j)*16+h]
  const int flat = o * 256 + c;
  const int h = flat >> 12, j = (flat >> 6) & 63, i = flat & 63;
  const int iy = i >> 3, ix = i & 7, jy = j >> 3, jx = j & 7;
  const int ridx = (iy - jy + 7) * 15 + (ix - jx + 7);
  biasT[flat] = rel[ridx * 16 + h];
}

// ---------------------------------------------------------------------------
// K1: qkv (MFMA) + windowed attention (per-wave, barrier-free phase 3).
// Wave w owns heads 4w..4w+3 (q/k/v channels 64w..64w+63).
// ---------------------------------------------------------------------------
__global__ __launch_bounds__(256) void k_attn(
    const float* __restrict__ x, const u16* __restrict__ w8,
    const float* __restrict__ biasT, u16* __restrict__ o_img)
{
  __shared__ __align__(16) union {
    u16 xb[64][264];   // phase 1-2: x window [px][c] bf16
    u16 P[4][4096];    // phase 3: per-wave P tile [i][j], XOR-swizzled
  } U;
  __shared__ __align__(16) u16 q_s[64][264];   // [px][ch], q pre-scaled 0.25
  __shared__ __align__(16) u16 k_s[64][264];   // [px][ch]
  __shared__ __align__(16) u16 v_sT[256][72];  // [ch][px]

  const int tid = threadIdx.x;
  const int nb  = blockIdx.x;
  const int b   = nb >> 10;
  const int hh  = (nb >> 5) & 31;
  const int ww  = nb & 31;
  const int h0  = hh << 3, w0 = ww << 3;

  // ---- phase 1: stage x window -> xb [px][c] bf16 ----
  {
    const int c2 = tid & 127;
    const int half = tid >> 7;
    const float* p0 = x + (((size_t)(b * C_ + 2 * c2)) * H_ + (h0 + half * 4)) * W_ + w0;
    const float* p1 = p0 + (size_t)H_ * W_;
#pragma unroll
    for (int r = 0; r < 4; ++r) {
      const float4 a0 = *(const float4*)(p0 + r * W_);
      const float4 a1 = *(const float4*)(p0 + r * W_ + 4);
      const float4 b0 = *(const float4*)(p1 + r * W_);
      const float4 b1 = *(const float4*)(p1 + r * W_ + 4);
      const float fa[8] = {a0.x, a0.y, a0.z, a0.w, a1.x, a1.y, a1.z, a1.w};
      const float fb[8] = {b0.x, b0.y, b0.z, b0.w, b1.x, b1.y, b1.z, b1.w};
      const int px0 = (half * 4 + r) * 8;
#pragma unroll
      for (int cc = 0; cc < 8; ++cc)
        *(u32*)&U.xb[px0 + cc][2 * c2] = pack2rn(fa[cc], fb[cc]);
    }
  }
  __syncthreads();

  // ---- phase 2: MFMA GEMM, wave w computes rows for its own heads ----
  const int lane = tid & 63, wid = tid >> 6;
  const int n = lane & 31, h5 = lane >> 5;

  f32x16 acc[6][2];
#pragma unroll
  for (int mt = 0; mt < 6; ++mt)
#pragma unroll
    for (int nt = 0; nt < 2; ++nt)
#pragma unroll
      for (int i = 0; i < 16; ++i) acc[mt][nt][i] = 0.f;

#pragma unroll 2
  for (int kb = 0; kb < 16; ++kb) {
    const int k0 = kb * 16;
    bf16x8 bfr[2];
#pragma unroll
    for (int nt = 0; nt < 2; ++nt) {
      union { uint4 u; bf16x8 v; } T;
      T.u = *(const uint4*)&U.xb[nt * 32 + n][k0 + h5 * 8];
      bfr[nt] = T.v;
    }
#pragma unroll
    for (int mt = 0; mt < 6; ++mt) {
      // q rows: wid*64.., k rows: 256+wid*64.., v rows: 512+wid*64..
      const int row = (mt >> 1) * 256 + wid * 64 + (mt & 1) * 32 + n;
      union { uint4 u; bf16x8 v; } A;
      A.u = *(const uint4*)(w8 + (size_t)row * 256 + k0 + h5 * 8);
      acc[mt][0] = __builtin_amdgcn_mfma_f32_32x32x16_bf16(A.v, bfr[0], acc[mt][0], 0, 0, 0);
      acc[mt][1] = __builtin_amdgcn_mfma_f32_32x32x16_bf16(A.v, bfr[1], acc[mt][1], 0, 0, 0);
    }
  }

  // ---- phase 2.5: scatter q,k -> [px][ch] (u32 pairs); v -> [ch][px] ----
  const int chb0 = wid * 64 + 4 * h5;
#pragma unroll
  for (int mt = 0; mt < 4; ++mt) {
    u16 (*dst)[264] = (mt < 2) ? q_s : k_s;
    const float qs = (mt < 2) ? 0.25f : 1.0f;
    const int chb = chb0 + (mt & 1) * 32;
#pragma unroll
    for (int nt = 0; nt < 2; ++nt) {
      const int px = nt * 32 + n;
#pragma unroll
      for (int m = 0; m < 8; ++m) {
        const int ch = chb + ((2 * m) & 3) + 8 * (m >> 1);
        *(u32*)&dst[px][ch] =
            pack2rn(acc[mt][nt][2 * m] * qs, acc[mt][nt][2 * m + 1] * qs);
      }
    }
  }
#pragma unroll
  for (int mt = 4; mt < 6; ++mt) {
    const int chb = chb0 + (mt & 1) * 32;
#pragma unroll
    for (int nt = 0; nt < 2; ++nt) {
      const int px = nt * 32 + n;
#pragma unroll
      for (int r = 0; r < 16; ++r) {
        const int ch = chb + (r & 3) + 8 * (r >> 2);
        v_sT[ch][px] = f2brn(acc[mt][nt][r]);
      }
    }
  }
  __syncthreads();  // protect xb->P union across all waves

  // ---- phase 3: per-wave attention, 4 heads, no barriers ----
  u16* Pw = U.P[wid];
  const int il = lane & 15, jg = lane >> 4;

  for (int hl = 0; hl < 4; ++hl) {
    const int head = wid * 4 + hl;
    const int hb = head * 16;

    // QK^T swapped: S^T[j][i] = K[j][d] . Q^T[d][i]   (scale folded into q)
    bf16x8 ak[2], bq[2];
#pragma unroll
    for (int jt = 0; jt < 2; ++jt) {
      union { uint4 u; bf16x8 v; } T;
      T.u = *(const uint4*)&k_s[jt * 32 + n][hb + h5 * 8];
      ak[jt] = T.v;
    }
#pragma unroll
    for (int it = 0; it < 2; ++it) {
      union { uint4 u; bf16x8 v; } T;
      T.u = *(const uint4*)&q_s[it * 32 + n][hb + h5 * 8];
      bq[it] = T.v;
    }
    f32x16 zro;
#pragma unroll
    for (int e = 0; e < 16; ++e) zro[e] = 0.f;
    f32x16 s[2][2];
#pragma unroll
    for (int jt = 0; jt < 2; ++jt)
#pragma unroll
      for (int it = 0; it < 2; ++it)
        s[jt][it] = __builtin_amdgcn_mfma_f32_32x32x16_bf16(ak[jt], bq[it], zro, 0, 0, 0);

    // + bias (biasT[head][j][i], coalesced over i = lanes)
    const float* bT = biasT + head * 4096;
#pragma unroll
    for (int jt = 0; jt < 2; ++jt)
#pragma unroll
      for (int it = 0; it < 2; ++it)
#pragma unroll
        for (int r = 0; r < 16; ++r) {
          const int j = jt * 32 + (r & 3) + 8 * (r >> 2) + 4 * h5;
          s[jt][it][r] += bT[j * 64 + it * 32 + n];
        }

    // in-lane softmax per i-row (lane pair n, n+32 holds the two j-halves)
#pragma unroll
    for (int it = 0; it < 2; ++it) {
      const int i = it * 32 + n;
      float mx = s[0][it][0];
#pragma unroll
      for (int jt = 0; jt < 2; ++jt)
#pragma unroll
        for (int r = 0; r < 16; ++r) mx = fmaxf(mx, s[jt][it][r]);
      mx = fmaxf(mx, __shfl_xor(mx, 32));
      float sum = 0.f;
#pragma unroll
      for (int jt = 0; jt < 2; ++jt)
#pragma unroll
        for (int r = 0; r < 16; ++r) {
          const float p = __expf(s[jt][it][r] - mx);
          s[jt][it][r] = p;
          sum += p;
        }
      sum += __shfl_xor(sum, 32);
      const float rs = 1.0f / sum;
      const u32 rowoff = (u32)(i * 128);
      const u32 swz = (u32)((i & 7) << 4);
#pragma unroll
      for (int jt = 0; jt < 2; ++jt)
#pragma unroll
        for (int m = 0; m < 8; ++m) {
          const int j = jt * 32 + ((2 * m) & 3) + 8 * (m >> 1) + 4 * h5;
          const u32 off = (rowoff + (u32)(j * 2)) ^ swz;
          *(u32*)((char*)Pw + off) =
              pack2rn(s[jt][it][2 * m] * rs, s[jt][it][2 * m + 1] * rs);
        }
    }

    // PV: O[64i][16d] = P[64x64] . V[64x16]  (16x16x32, N = d = 16 exactly)
    bf16x8 bv[2];
#pragma unroll
    for (int ks = 0; ks < 2; ++ks) {
      union { uint4 u; bf16x8 v; } T;
      T.u = *(const uint4*)&v_sT[hb + il][ks * 32 + jg * 8];
      bv[ks] = T.v;
    }
#pragma unroll
    for (int it2 = 0; it2 < 4; ++it2) {
      f32x4 pv = {0.f, 0.f, 0.f, 0.f};
#pragma unroll
      for (int ks = 0; ks < 2; ++ks) {
        const int i = it2 * 16 + il;
        const u32 off =
            ((u32)(i * 128 + ks * 64 + jg * 16)) ^ ((u32)((i & 7) << 4));
        union { uint4 u; bf16x8 v; } A;
        A.u = *(const uint4*)((const char*)Pw + off);
        pv = __builtin_amdgcn_mfma_f32_16x16x32_bf16(A.v, bv[ks], pv, 0, 0, 0);
      }
#pragma unroll
      for (int rr = 0; rr < 4; ++rr) {
        const int i = it2 * 16 + jg * 4 + rr;
        const int iy = i >> 3, ix = i & 7;
        o_img[(((size_t)(b * H_ + h0 + iy)) * W_ + (w0 + ix)) * C_ + hb + il] =
            f2brn(pv[rr]);
      }
    }
  }
}

// ---------------------------------------------------------------------------
// K2 (MFMA): out1 = ox + oy + bx + by.
// Round 13: 4 output rows per wave (acc[4][2][2] = 256 AGPR), 1 block/CU,
// launch_bounds(256,1) -> 512-VGPR budget. A-fragment reuse 8x (4r x 2nt).
// 11-row halo; dbuf gload_lds DMA staging (r12); XCD swizzle (512 = 8x64).
// ---------------------------------------------------------------------------
__global__ __launch_bounds__(256, 1) void k_conv2m(
    const u16* __restrict__ o_nhwc, const u16* __restrict__ wt,
    const float* __restrict__ bxg, const float* __restrict__ byg,
    u16* __restrict__ out1)
{
  __shared__ u16 tile[2][2][1496 * 8];   // 95744 B
  __shared__ float bias_l[128];

  const int tid = threadIdx.x;
  // XCD swizzle: 512 blocks = 8 XCDs x 64 contiguous ids (bijective)
  const int nb = (blockIdx.x & 7) * 64 + (blockIdx.x >> 3);
  const int wh = nb & 1, oh = (nb >> 1) & 1, hg = (nb >> 2) & 63, b = nb >> 8;
  const int h0 = hg << 2;             // 4 output rows h0..h0+3
  const int ob = oh * 128, wb0 = wh * 128;
  const int lane = tid & 63, wid = tid >> 6;
  const int o64 = (wid & 1) * 64;         // wave M-tile
  const int w64 = ((wid >> 1) & 1) * 64;  // wave N (w) tile
  const int n = lane & 31, h5 = lane >> 5;

  if (tid < 128) bias_l[tid] = bxg[ob + tid] + byg[ob + tid];

  // ---- per-lane staging source (reflect-clamped); cell e = tid + k*256 ----
  const u16* srcp[6];
#pragma unroll
  for (int k = 0; k < 6; ++k) {
    const int e = tid + (k << 8);
    srcp[k] = nullptr;
    if (e < 1496) {
      const int r = e / 136, wi = e - r * 136;
      const int hp = h0 - 3 + r;            // r 0..10
      const int wp = wb0 + wi - 4;
      if (hp >= 0 && hp <= 256 && wp >= 0 && wp <= 256) {
        const int hr = (hp == 256) ? 254 : hp;
        const int wr = (wp == 256) ? 254 : wp;
        srcp[k] = o_nhwc + (((size_t)(b * H_ + hr)) * W_ + wr) * C_;
      }
    }
  }

  // ---- zero OOB cells once (chunk-invariant; both buffers, both planes) ----
#pragma unroll
  for (int k = 0; k < 6; ++k) {
    const int e = tid + (k << 8);
    if (e < 1496 && srcp[k] == nullptr) {
      const uint4 z = make_uint4(0, 0, 0, 0);
      *(uint4*)&tile[0][0][e * 8] = z;
      *(uint4*)&tile[0][1][e * 8] = z;
      *(uint4*)&tile[1][0][e * 8] = z;
      *(uint4*)&tile[1][1][e * 8] = z;
    }
  }

  // ---- async stage of one 16-channel chunk into buffer `buf` ----
  auto stage = [&](int buf, int c0) {
#pragma unroll
    for (int k = 0; k < 6; ++k) {
      const int e = tid + (k << 8);
      u16* l0 = &tile[buf][0][(size_t)(k * 256 + wid * 64) * 8];
      u16* l1 = &tile[buf][1][(size_t)(k * 256 + wid * 64) * 8];
      if (e < 1496 && srcp[k]) {
        gl_lds16(srcp[k] + c0,     l0);
        gl_lds16(srcp[k] + c0 + 8, l1);
      }
    }
  };

  f32x16 acc[4][2][2];   // [row][mt][nt] -- 256 AGPR
#pragma unroll
  for (int r2 = 0; r2 < 4; ++r2)
#pragma unroll
    for (int mt = 0; mt < 2; ++mt)
#pragma unroll
      for (int nt = 0; nt < 2; ++nt)
#pragma unroll
        for (int i = 0; i < 16; ++i) acc[r2][mt][nt][i] = 0.f;

  // prologue: stage chunk 0
  stage(0, 0);
  __syncthreads();

  int cur = 0;
  for (int cb = 0; cb < 16; ++cb) {
    const int c0 = cb * 16;
    if (cb < 15) stage(cur ^ 1, c0 + 16);   // DMA: cannot be sunk
    // ---- compute: 2 convs x 8 taps, 4 rows x 2 mt x 2 nt MFMA each ----
#pragma unroll
    for (int cv = 0; cv < 2; ++cv) {
      const u16* wbase = wt + (size_t)cv * 524288;
#pragma unroll
      for (int t = 0; t < 8; ++t) {
        bf16x8 a[2];
#pragma unroll
        for (int mt = 0; mt < 2; ++mt) {
          const int o = ob + o64 + mt * 32 + n;
          union { uint4 u; bf16x8 v; } Uu;
          Uu.u = *(const uint4*)(wbase + ((size_t)(t * 256 + o)) * 256 + c0 + h5 * 8);
          a[mt] = Uu.v;
        }
#pragma unroll
        for (int r2 = 0; r2 < 4; ++r2) {
          bf16x8 bb[2];
#pragma unroll
          for (int nt = 0; nt < 2; ++nt) {
            const int rr = cv ? (r2 + 3) : (r2 + t);
            const int wi = w64 + nt * 32 + n + (cv ? (t + 1) : 4);
            union { uint4 u; bf16x8 v; } Uu;
            Uu.u = *(const uint4*)&tile[cur][h5][(size_t)(rr * 136 + wi) * 8];
            bb[nt] = Uu.v;
          }
          acc[r2][0][0] = __builtin_amdgcn_mfma_f32_32x32x16_bf16(a[0], bb[0], acc[r2][0][0], 0, 0, 0);
          acc[r2][0][1] = __builtin_amdgcn_mfma_f32_32x32x16_bf16(a[0], bb[1], acc[r2][0][1], 0, 0, 0);
          acc[r2][1][0] = __builtin_amdgcn_mfma_f32_32x32x16_bf16(a[1], bb[0], acc[r2][1][0], 0, 0, 0);
          acc[r2][1][1] = __builtin_amdgcn_mfma_f32_32x32x16_bf16(a[1], bb[1], acc[r2][1][1], 0, 0, 0);
        }
      }
    }
    __syncthreads();   // drains DMA vmcnt + syncs; next buf ready
    cur ^= 1;
  }
  // ---- epilogue: +bias, bf16, NCHW, 4 rows ----
#pragma unroll
  for (int r2 = 0; r2 < 4; ++r2)
#pragma unroll
    for (int mt = 0; mt < 2; ++mt)
#pragma unroll
      for (int nt = 0; nt < 2; ++nt)
#pragma unroll
        for (int r = 0; r < 16; ++r) {
          const int om = o64 + mt * 32 + (r & 3) + 8 * (r >> 2) + 4 * h5;
          const int o = ob + om;
          const int wg = wb0 + w64 + nt * 32 + n;
          const float v = acc[r2][mt][nt][r] + bias_l[om];
          out1[(((size_t)(b * C_ + o)) * H_ + (h0 + r2)) * W_ + wg] = f2b(v);
        }
}

// ---------------------------------------------------------------------------
// K3: depthwise 8x8 conv + BN (unchanged).
// ---------------------------------------------------------------------------
__global__ __launch_bounds__(256) void k_dwbn(
    const u16* __restrict__ out1, const float* __restrict__ wdw,
    const float* __restrict__ gam, const float* __restrict__ bet,
    const float* __restrict__ mea, const float* __restrict__ var,
    u16* __restrict__ bno)
{
  __shared__ u16 tile[23][264];
  const int tid = threadIdx.x, nb = blockIdx.x;
  const int c = nb & 255, ht = (nb >> 8) & 15, b = nb >> 12;
  const int h0 = ht * 16;

  for (int e = tid; e < 23 * 264; e += 256) {
    const int tr = e / 264, tc = e % 264;
    const int r = h0 - 3 + tr;
    const int cg = tc - 3;
    u16 v = 0;
    if (r >= 0 && r <= 256 && cg >= 0 && cg <= 256) {
      const int rr = (r == 256) ? 254 : r;
      const int cgm = (cg == 256) ? 254 : cg;
      v = out1[(((size_t)(b * C_ + c)) * H_ + rr) * W_ + cgm];
    }
    tile[tr][tc] = v;
  }
  float wk[64];
#pragma unroll
  for (int k2 = 0; k2 < 64; ++k2) wk[k2] = wdw[c * 64 + k2];
  const float scl = gam[c] / sqrtf(var[c] + 1e-5f);
  const float shf = bet[c] - mea[c] * scl;
  __syncthreads();

  const int wg = tid & 31, hg = tid >> 5;
  const int w0 = wg * 8;
#pragma unroll
  for (int k = 0; k < 2; ++k) {
    const int hl = hg * 2 + k;
    float a[8];
#pragma unroll
    for (int s = 0; s < 8; ++s) a[s] = 0.f;
#pragma unroll
    for (int i = 0; i < 8; ++i) {
      const uint4 va = *(const uint4*)&tile[hl + i][w0];
      const uint4 vb = *(const uint4*)&tile[hl + i][w0 + 8];
      float f[16];
      f[0] = b2f_lo(va.x);  f[1] = b2f_hi(va.x);  f[2] = b2f_lo(va.y);  f[3] = b2f_hi(va.y);
      f[4] = b2f_lo(va.z);  f[5] = b2f_hi(va.z);  f[6] = b2f_lo(va.w);  f[7] = b2f_hi(va.w);
      f[8] = b2f_lo(vb.x);  f[9] = b2f_hi(vb.x);  f[10] = b2f_lo(vb.y); f[11] = b2f_hi(vb.y);
      f[12] = b2f_lo(vb.z); f[13] = b2f_hi(vb.z); f[14] = b2f_lo(vb.w); f[15] = b2f_hi(vb.w);
#pragma unroll
      for (int j = 0; j < 8; ++j) {
        const float wv = wk[i * 8 + j];
#pragma unroll
        for (int s = 0; s < 8; ++s) a[s] += f[s + j] * wv;
      }
    }
    uint4 uv;
    uv.x = pack2(a[0] * scl + shf, a[1] * scl + shf);
    uv.y = pack2(a[2] * scl + shf, a[3] * scl + shf);
    uv.z = pack2(a[4] * scl + shf, a[5] * scl + shf);
    uv.w = pack2(a[6] * scl + shf, a[7] * scl + shf);
    *(uint4*)&bno[(((size_t)(b * C_ + c)) * H_ + h0 + hl) * W_ + w0] = uv;
  }
}

// ---------------------------------------------------------------------------
// K4 (MFMA): 1x1 projection (unchanged). Output f32.
// ---------------------------------------------------------------------------
__global__ __launch_bounds__(256) void k_projm(
    const u16* __restrict__ bn, const float* __restrict__ wp, float* __restrict__ out)
{
  const int tid = threadIdx.x, nb = blockIdx.x;
  const int oh = nb & 1;
  const int pb = nb >> 1;            // 0..1023
  const int b  = pb >> 9;
  const int px0 = (pb & 511) << 7;   // 128-px slab (linear in NCHW plane)
  const int lane = tid & 63, wid = tid >> 6;
  const int wo = (wid >> 1) * 64, wpx = (wid & 1) * 64;
  const int n = lane & 31, h5 = lane >> 5;
  const int ob = oh * 128;
  const int pxl = px0 + wpx + n;

  f32x16 acc[2][2];
#pragma unroll
  for (int mt = 0; mt < 2; ++mt)
#pragma unroll
    for (int nt = 0; nt < 2; ++nt)
#pragma unroll
      for (int i = 0; i < 16; ++i) acc[mt][nt][i] = 0.f;

  const u16* bnb = bn + (size_t)b * C_ * HW_;
#pragma unroll 2
  for (int cb = 0; cb < 16; ++cb) {
    const int c0 = cb * 16;
    bf16x8 a[2];
#pragma unroll
    for (int mt = 0; mt < 2; ++mt) {
      const int row = ob + wo + mt * 32 + n;
      const float4 w0v = *(const float4*)&wp[(size_t)row * 256 + c0 + h5 * 8];
      const float4 w1v = *(const float4*)&wp[(size_t)row * 256 + c0 + h5 * 8 + 4];
      union { u32 u[4]; bf16x8 v; } T;
      T.u[0] = pack2rn(w0v.x, w0v.y);
      T.u[1] = pack2rn(w0v.z, w0v.w);
      T.u[2] = pack2rn(w1v.x, w1v.y);
      T.u[3] = pack2rn(w1v.z, w1v.w);
      a[mt] = T.v;
    }
    bf16x8 bb[2];
#pragma unroll
    for (int nt = 0; nt < 2; ++nt) {
      const u16* sp = bnb + (size_t)(c0 + h5 * 8) * HW_ + (pxl + nt * 32);
      const u32 e0 = sp[0 * HW_], e1 = sp[1 * HW_], e2 = sp[2 * HW_], e3 = sp[3 * HW_];
      const u32 e4 = sp[4 * HW_], e5 = sp[5 * HW_], e6 = sp[6 * HW_], e7 = sp[7 * HW_];
      union { u32 u[4]; bf16x8 v; } T;
      T.u[0] = e0 | (e1 << 16);
      T.u[1] = e2 | (e3 << 16);
      T.u[2] = e4 | (e5 << 16);
      T.u[3] = e6 | (e7 << 16);
      bb[nt] = T.v;
    }
    acc[0][0] = __builtin_amdgcn_mfma_f32_32x32x16_bf16(a[0], bb[0], acc[0][0], 0, 0, 0);
    acc[0][1] = __builtin_amdgcn_mfma_f32_32x32x16_bf16(a[0], bb[1], acc[0][1], 0, 0, 0);
    acc[1][0] = __builtin_amdgcn_mfma_f32_32x32x16_bf16(a[1], bb[0], acc[1][0], 0, 0, 0);
    acc[1][1] = __builtin_amdgcn_mfma_f32_32x32x16_bf16(a[1], bb[1], acc[1][1], 0, 0, 0);
  }
#pragma unroll
  for (int mt = 0; mt < 2; ++mt)
#pragma unroll
    for (int nt = 0; nt < 2; ++nt)
#pragma unroll
      for (int r = 0; r < 16; ++r) {
        const int o = ob + wo + mt * 32 + (r & 3) + 8 * (r >> 2) + 4 * h5;
        out[((size_t)(b * C_ + o)) * HW_ + (pxl + nt * 32)] = acc[mt][nt][r];
      }
}

// ---------------------------------------------------------------------------
extern "C" void kernel_launch(void* const* d_in, const int* in_sizes, int n_in,
                              void* d_out, int out_size, void* d_ws, size_t ws_size,
                              hipStream_t stream)
{
  const float* x     = (const float*)d_in[0];
  const float* wqkv  = (const float*)d_in[1];
  const float* rel   = (const float*)d_in[2];
  const float* wax   = (const float*)d_in[3];
  const float* bax   = (const float*)d_in[4];
  const float* way   = (const float*)d_in[5];
  const float* bay   = (const float*)d_in[6];
  const float* wdw   = (const float*)d_in[7];
  const float* gam   = (const float*)d_in[8];
  const float* bet   = (const float*)d_in[9];
  const float* mea   = (const float*)d_in[10];
  const float* var   = (const float*)d_in[11];
  const float* wproj = (const float*)d_in[12];
  float* out = (float*)d_out;

  const size_t N = (size_t)B_ * C_ * H_ * W_;
  u16* oNHWC  = (u16*)d_out;        // bf16 o, NHWC (first half of f32 out)
  u16* out1b  = (u16*)d_out + N;    // bf16 out1, NCHW (second half)
  u16* wtbuf  = (u16*)d_ws;         // WT 2MB + w8 384KB (bf16)
  float* biasT = (float*)((char*)d_ws + 2490368);  // 256KB, after WT+w8
  u16* bnbuf  = (u16*)d_ws;         // bn NCHW bf16 (reuses region after K2)

  hipLaunchKernelGGL(k_wt,     dim3(256),  dim3(256), 0, stream, wax, way, wqkv, rel, wtbuf, biasT);
  hipLaunchKernelGGL(k_attn,   dim3(2048), dim3(256), 0, stream, x, wtbuf + 1048576, biasT, oNHWC);
  hipLaunchKernelGGL(k_conv2m, dim3(512),  dim3(256), 0, stream, oNHWC, wtbuf, bax, bay, out1b);
  hipLaunchKernelGGL(k_dwbn,   dim3(8192), dim3(256), 0, stream, out1b, wdw, gam, bet, mea, var, bnbuf);
  hipLaunchKernelGGL(k_projm,  dim3(2048), dim3(256), 0, stream, bnbuf, wproj, out);
}